// Round 1
// baseline (1294.810 us; speedup 1.0000x reference)
//
#include <hip/hip_runtime.h>
#include <cstdint>
#include <cstddef>

#define PSP 110592          // 48*48*48 spatial positions per batch
#define NCH 128             // C_I
#define NB  2               // batch
static constexpr float EPSV = 1e-5f;

// ---------------------------------------------------------------------------
// Transpose the six 128x128 weight matrices into (c,o) layout for the GEMMs.
// ---------------------------------------------------------------------------
__global__ __launch_bounds__(256) void transpose6_kernel(
    const float* __restrict__ w0, const float* __restrict__ w1,
    const float* __restrict__ w2, const float* __restrict__ w3,
    const float* __restrict__ w4, const float* __restrict__ w5,
    float* __restrict__ wt)
{
    const float* src = w0;
    if (blockIdx.x == 1) src = w1;
    else if (blockIdx.x == 2) src = w2;
    else if (blockIdx.x == 3) src = w3;
    else if (blockIdx.x == 4) src = w4;
    else if (blockIdx.x == 5) src = w5;
    float* dst = wt + blockIdx.x * NCH * NCH;
    for (int idx = threadIdx.x; idx < NCH * NCH; idx += 256) {
        int o = idx >> 7, c = idx & 127;
        dst[c * NCH + o] = src[idx];
    }
}

// ---------------------------------------------------------------------------
// k/v projections: k[b][o][l] = sum_c Wk[o][c]*lang[b][c][l] + bk[o]
// 2 tensors * 2 batches * 128 o * 20 l = 10240 outputs, 256 MACs each.
// ---------------------------------------------------------------------------
__global__ __launch_bounds__(256) void kv_kernel(
    const float* __restrict__ lang,
    const float* __restrict__ Wk, const float* __restrict__ bk,
    const float* __restrict__ Wv, const float* __restrict__ bv,
    float* __restrict__ kout, float* __restrict__ vout)
{
    int gid = blockIdx.x * 256 + threadIdx.x;     // 0..10239
    int sel = gid / 5120;                          // 0 = k, 1 = v
    int r   = gid % 5120;
    int b   = r / 2560;
    int o   = (r % 2560) / 20;
    int l   = r % 20;
    const float* W  = sel ? Wv : Wk;
    const float* bb = sel ? bv : bk;
    const float* lg = lang + b * 256 * 20 + l;
    float acc = bb[o];
    #pragma unroll 8
    for (int c = 0; c < 256; ++c)
        acc = fmaf(W[o * 256 + c], lg[c * 20], acc);
    (sel ? vout : kout)[b * 2560 + o * 20 + l] = acc;
}

// ---------------------------------------------------------------------------
// Templated GEMM: out[b][o][p] = epi( sum_c W[o][c]*in[b][c][p] + bias[o] )
// in channel-major (b,128,PSP). Wt is (c,o) transposed. Tile: 128 o x 64 p.
// MODE 0: store raw (+bias), accumulate per-(b,o) sum/sumsq atomics
// MODE 1: input = norm(in)*norm(in2) computed on the fly (stats given); ReLU
// MODE 2: ReLU
// MODE 3: out = mulbuf * tanh(raw + bias)   (final output)
// ---------------------------------------------------------------------------
template<int MODE>
__global__ __launch_bounds__(256) void gemm_k128(
    const float* __restrict__ in, const float* __restrict__ Wt,
    const float* __restrict__ bias, float* __restrict__ out,
    float* __restrict__ s_sum, float* __restrict__ s_sq,
    const float* __restrict__ in2,
    const float* __restrict__ stA, const float* __restrict__ stA2,
    const float* __restrict__ stB, const float* __restrict__ stB2,
    const float* __restrict__ mulbuf)
{
    __shared__ float wl[32][NCH];   // Wt chunk: [c-within-chunk][o]
    __shared__ float xl[32][64];    // input chunk: [c-within-chunk][p]
    __shared__ float nrm[4][NCH];   // MODE 1: mA, rA, mB, rB

    const int t = threadIdx.x;
    const int b = blockIdx.y;
    const int pblk = blockIdx.x * 64;
    const size_t bbase = (size_t)b * NCH * PSP;

    if constexpr (MODE == 1) {
        if (t < NCH) {
            float m = stA[b * NCH + t] * (1.0f / PSP);
            float v = stA2[b * NCH + t] * (1.0f / PSP) - m * m;
            nrm[0][t] = m;
            nrm[1][t] = rsqrtf(v + EPSV);
        } else {
            int c = t - NCH;
            float m = stB[b * NCH + c] * (1.0f / PSP);
            float v = stB2[b * NCH + c] * (1.0f / PSP) - m * m;
            nrm[2][c] = m;
            nrm[3][c] = rsqrtf(v + EPSV);
        }
        __syncthreads();
    }

    const int o0 = (t >> 3) << 2;   // 4*(t/8)  : 0..124
    const int p0 = (t & 7) << 3;    // 8*(t%8)  : 0..56

    float acc[4][8];
    #pragma unroll
    for (int j = 0; j < 4; ++j)
        #pragma unroll
        for (int i = 0; i < 8; ++i) acc[j][i] = 0.0f;

    for (int cc = 0; cc < NCH; cc += 32) {
        // stage W chunk (contiguous 32*128 floats)
        {
            const float4* src = (const float4*)(Wt + cc * NCH);
            float4* dst = (float4*)(&wl[0][0]);
            #pragma unroll
            for (int i = 0; i < 4; ++i) dst[t + 256 * i] = src[t + 256 * i];
        }
        // stage input chunk [cc..cc+32) x [pblk..pblk+64)
        #pragma unroll
        for (int i = 0; i < 2; ++i) {
            int idx = t + 256 * i;          // float4 slot 0..511
            int r   = idx >> 4;             // 0..31
            int cp  = (idx & 15) << 2;      // 0..60
            int c   = cc + r;
            float4 v = *(const float4*)(in + bbase + (size_t)c * PSP + pblk + cp);
            if constexpr (MODE == 1) {
                float4 v2 = *(const float4*)(in2 + bbase + (size_t)c * PSP + pblk + cp);
                float ma = nrm[0][c], ra = nrm[1][c];
                float mb = nrm[2][c], rb = nrm[3][c];
                v.x = ((v.x - ma) * ra) * ((v2.x - mb) * rb);
                v.y = ((v.y - ma) * ra) * ((v2.y - mb) * rb);
                v.z = ((v.z - ma) * ra) * ((v2.z - mb) * rb);
                v.w = ((v.w - ma) * ra) * ((v2.w - mb) * rb);
            }
            *(float4*)(&xl[r][cp]) = v;
        }
        __syncthreads();
        #pragma unroll
        for (int c = 0; c < 32; ++c) {
            float4 wv = *(const float4*)(&wl[c][o0]);
            float4 xa = *(const float4*)(&xl[c][p0]);
            float4 xb = *(const float4*)(&xl[c][p0 + 4]);
            float wj[4] = {wv.x, wv.y, wv.z, wv.w};
            float xi[8] = {xa.x, xa.y, xa.z, xa.w, xb.x, xb.y, xb.z, xb.w};
            #pragma unroll
            for (int j = 0; j < 4; ++j)
                #pragma unroll
                for (int i = 0; i < 8; ++i)
                    acc[j][i] = fmaf(wj[j], xi[i], acc[j][i]);
        }
        __syncthreads();
    }

    const float4 bv4 = *(const float4*)(bias + o0);
    const float bj[4] = {bv4.x, bv4.y, bv4.z, bv4.w};

    #pragma unroll
    for (int j = 0; j < 4; ++j) {
        const int o = o0 + j;
        float vals[8];
        #pragma unroll
        for (int i = 0; i < 8; ++i) vals[i] = acc[j][i] + bj[j];
        if constexpr (MODE == 1 || MODE == 2) {
            #pragma unroll
            for (int i = 0; i < 8; ++i) vals[i] = fmaxf(vals[i], 0.0f);
        }
        if constexpr (MODE == 3) {
            const float* mb = mulbuf + bbase + (size_t)o * PSP + pblk + p0;
            float4 m0 = *(const float4*)mb;
            float4 m1 = *(const float4*)(mb + 4);
            float mm[8] = {m0.x, m0.y, m0.z, m0.w, m1.x, m1.y, m1.z, m1.w};
            #pragma unroll
            for (int i = 0; i < 8; ++i) vals[i] = mm[i] * tanhf(vals[i]);
        }
        float* dst = out + bbase + (size_t)o * PSP + pblk + p0;
        *(float4*)dst       = make_float4(vals[0], vals[1], vals[2], vals[3]);
        *(float4*)(dst + 4) = make_float4(vals[4], vals[5], vals[6], vals[7]);
        if constexpr (MODE == 0) {
            float s = 0.0f, sq = 0.0f;
            #pragma unroll
            for (int i = 0; i < 8; ++i) { s += vals[i]; sq += vals[i] * vals[i]; }
            #pragma unroll
            for (int off = 1; off < 8; off <<= 1) {
                s  += __shfl_xor(s, off, 8);
                sq += __shfl_xor(sq, off, 8);
            }
            if ((t & 7) == 0) {
                atomicAdd(&s_sum[b * NCH + o], s);
                atomicAdd(&s_sq[b * NCH + o], sq);
            }
        }
    }
}

// ---------------------------------------------------------------------------
// Attention: per position p, normalize q (stats from GEMM1), per head:
// sim = 0.25 * qn . k ; softmax over L=20 ; x = attn . v
// x written in (p, c) order -> flat buffer IS x_img in (c, p) order.
// k/v indices are wave-uniform -> compiler scalarizes (SGPR operands).
// ---------------------------------------------------------------------------
__global__ __launch_bounds__(256) void attn_kernel(
    const float* __restrict__ q_pre, const float* __restrict__ kbuf,
    const float* __restrict__ vbuf, const float* __restrict__ qsum,
    const float* __restrict__ qsq, float* __restrict__ xout)
{
    __shared__ float mq[NCH], rq[NCH];
    const int t = threadIdx.x;
    const int b = blockIdx.y;
    if (t < NCH) {
        float m = qsum[b * NCH + t] * (1.0f / PSP);
        float v = qsq[b * NCH + t] * (1.0f / PSP) - m * m;
        mq[t] = m;
        rq[t] = rsqrtf(v + EPSV) * 0.25f;   // fold attention scale into q-norm
    }
    __syncthreads();

    const int p = blockIdx.x * 256 + t;
    const float* qb = q_pre + (size_t)b * NCH * PSP + p;
    const float* kb = kbuf + b * (NCH * 20);
    const float* vb = vbuf + b * (NCH * 20);
    float* xb = xout + (size_t)b * NCH * PSP + (size_t)p * NCH;

    #pragma unroll 1
    for (int h = 0; h < 8; ++h) {
        float qn[16];
        #pragma unroll
        for (int j = 0; j < 16; ++j) {
            int c = h * 16 + j;
            qn[j] = (qb[(size_t)c * PSP] - mq[c]) * rq[c];
        }
        float sim[20];
        #pragma unroll
        for (int l = 0; l < 20; ++l) sim[l] = 0.0f;
        #pragma unroll
        for (int j = 0; j < 16; ++j) {
            const int c = h * 16 + j;
            #pragma unroll
            for (int l = 0; l < 20; ++l)
                sim[l] = fmaf(qn[j], kb[c * 20 + l], sim[l]);
        }
        float mx = sim[0];
        #pragma unroll
        for (int l = 1; l < 20; ++l) mx = fmaxf(mx, sim[l]);
        float se = 0.0f;
        #pragma unroll
        for (int l = 0; l < 20; ++l) {
            float e = __expf(sim[l] - mx);
            sim[l] = e;
            se += e;
        }
        float inv = 1.0f / se;
        float x[16];
        #pragma unroll
        for (int j = 0; j < 16; ++j) {
            int c = h * 16 + j;
            float a = 0.0f;
            #pragma unroll
            for (int l = 0; l < 20; ++l)
                a = fmaf(sim[l], vb[c * 20 + l], a);
            x[j] = a * inv;
        }
        #pragma unroll
        for (int q4 = 0; q4 < 4; ++q4)
            *(float4*)(xb + h * 16 + q4 * 4) =
                make_float4(x[q4*4], x[q4*4+1], x[q4*4+2], x[q4*4+3]);
    }
}

// ---------------------------------------------------------------------------
extern "C" void kernel_launch(void* const* d_in, const int* in_sizes, int n_in,
                              void* d_out, int out_size, void* d_ws, size_t ws_size,
                              hipStream_t stream)
{
    const float* img  = (const float*)d_in[0];
    const float* lang = (const float*)d_in[1];
    const float* Wq   = (const float*)d_in[2];
    const float* bq   = (const float*)d_in[3];
    const float* Wk   = (const float*)d_in[4];
    const float* bk   = (const float*)d_in[5];
    const float* Wv   = (const float*)d_in[6];
    const float* bv   = (const float*)d_in[7];
    const float* Wpw  = (const float*)d_in[8];
    const float* bpw  = (const float*)d_in[9];
    const float* Wpi  = (const float*)d_in[10];
    const float* bpi  = (const float*)d_in[11];
    const float* Wpo  = (const float*)d_in[12];
    const float* bpo  = (const float*)d_in[13];
    const float* Wg1  = (const float*)d_in[14];
    const float* bg1  = (const float*)d_in[15];
    const float* Wg2  = (const float*)d_in[16];
    const float* bg2  = (const float*)d_in[17];
    float* outp = (float*)d_out;

    const size_t N = (size_t)NB * NCH * PSP;      // 28,311,552 elements
    // ws layout: bufA[N], bufB[N], wt[6*16384], k[2*2560], v[2*2560], stats[6*256]
    const size_t needed = (2 * N + 6 * 16384 + 2 * 2560 * 2 + 6 * 256) * sizeof(float);
    if (ws_size < needed) return;   // insufficient scratch -> loud validation failure

    float* bufA = (float*)d_ws;
    float* bufB = bufA + N;
    float* wt   = bufB + N;
    float* kbuf = wt + 6 * 16384;
    float* vbuf = kbuf + 2 * 2560;
    float* st   = vbuf + 2 * 2560;
    float* qs   = st;            // q sum
    float* qs2  = st + 256;      // q sumsq
    float* ss   = st + 512;      // skip sum
    float* ss2  = st + 768;
    float* wsu  = st + 1024;     // weight sum
    float* ws2  = st + 1280;

    hipMemsetAsync(st, 0, 6 * 256 * sizeof(float), stream);

    transpose6_kernel<<<dim3(6), dim3(256), 0, stream>>>(Wq, Wpi, Wpw, Wpo, Wg1, Wg2, wt);
    kv_kernel<<<dim3(40), dim3(256), 0, stream>>>(lang, Wk, bk, Wv, bv, kbuf, vbuf);

    const dim3 gg(PSP / 64, NB), gb(256);

    // GEMM1: q_pre = Wq*img (+stats) -> bufA
    gemm_k128<0><<<gg, gb, 0, stream>>>(img, wt + 0 * 16384, bq, bufA,
                                        qs, qs2, nullptr, nullptr, nullptr,
                                        nullptr, nullptr, nullptr);
    // attention: bufA -> bufB (x in (p,c) flat order == x_img channel-major)
    attn_kernel<<<dim3(PSP / 256, NB), gb, 0, stream>>>(bufA, kbuf, vbuf, qs, qs2, bufB);
    // GEMM2: skip_pre = Wpi*img (+stats) -> bufA
    gemm_k128<0><<<gg, gb, 0, stream>>>(img, wt + 1 * 16384, bpi, bufA,
                                        ss, ss2, nullptr, nullptr, nullptr,
                                        nullptr, nullptr, nullptr);
    // GEMM3: weight_pre = Wpw*x_img (+stats) -> d_out (scratch)
    gemm_k128<0><<<gg, gb, 0, stream>>>(bufB, wt + 2 * 16384, bpw, outp,
                                        wsu, ws2, nullptr, nullptr, nullptr,
                                        nullptr, nullptr, nullptr);
    // GEMM4: out = relu(Wpo * (norm(skip_pre)*norm(weight_pre))) -> bufB
    gemm_k128<1><<<gg, gb, 0, stream>>>(bufA, wt + 3 * 16384, bpo, bufB,
                                        nullptr, nullptr, outp,
                                        ss, ss2, wsu, ws2, nullptr);
    // GEMM5: relu1 = relu(Wg1*out) -> bufA
    gemm_k128<2><<<gg, gb, 0, stream>>>(bufB, wt + 4 * 16384, bg1, bufA,
                                        nullptr, nullptr, nullptr, nullptr, nullptr,
                                        nullptr, nullptr, nullptr);
    // GEMM6: final = out * tanh(Wg2*relu1 + bg2) -> d_out
    gemm_k128<3><<<gg, gb, 0, stream>>>(bufA, wt + 5 * 16384, bg2, outp,
                                        nullptr, nullptr, nullptr, nullptr, nullptr,
                                        nullptr, nullptr, bufB);
}

// Round 2
// 641.470 us; speedup vs baseline: 2.0185x; 2.0185x over previous
//
#include <hip/hip_runtime.h>
#include <cstdint>
#include <cstddef>

#define PSP 110592          // 48*48*48 positions per batch
#define NCH 128
#define NB  2
static constexpr float EPSV = 1e-5f;

typedef short bf16x8 __attribute__((ext_vector_type(8)));
typedef float f32x4  __attribute__((ext_vector_type(4)));
typedef float f32x2  __attribute__((ext_vector_type(2)));

__device__ __forceinline__ short f2bf(float f) {
    uint32_t u = __builtin_bit_cast(uint32_t, f);
    u += 0x7FFF + ((u >> 16) & 1);          // RNE
    return (short)(u >> 16);
}
__device__ __forceinline__ float bf2f(short s) {
    uint32_t u = ((uint32_t)(uint16_t)s) << 16;
    return __builtin_bit_cast(float, u);
}

// ---------------------------------------------------------------------------
// k/v projections (tiny, f32): k[b][o][l] = sum_c Wk[o][c]*lang[b][c][l]+bk[o]
// ---------------------------------------------------------------------------
__global__ __launch_bounds__(256) void kv_kernel(
    const float* __restrict__ lang,
    const float* __restrict__ Wk, const float* __restrict__ bk,
    const float* __restrict__ Wv, const float* __restrict__ bv,
    float* __restrict__ kout, float* __restrict__ vout)
{
    int gid = blockIdx.x * 256 + threadIdx.x;     // 0..10239
    int sel = gid / 5120;
    int r   = gid % 5120;
    int b   = r / 2560;
    int o   = (r % 2560) / 20;
    int l   = r % 20;
    const float* W  = sel ? Wv : Wk;
    const float* bb = sel ? bv : bk;
    const float* lg = lang + b * 256 * 20 + l;
    float acc = bb[o];
    #pragma unroll 8
    for (int c = 0; c < 256; ++c)
        acc = fmaf(W[o * 256 + c], lg[c * 20], acc);
    (sel ? vout : kout)[b * 2560 + o * 20 + l] = acc;
}

// ---------------------------------------------------------------------------
// MFMA GEMM: out[b][o][p] = epi( sum_c W[o][c]*in[b][c][p] + bias[o] )
// inputs c-major. W f32 row-major (o,c) read directly into A-fragments.
// Tile: 128 o x 64 p per block (4 waves, each wave 32 o x 64 p).
// MODE 0: store bf16 raw(+bias), per-(b,o) sum/sumsq atomics (f32 acc values)
// MODE 1: input = norm(inA)*norm(inB) on the fly (stats given); ReLU out
// MODE 2: ReLU out
// MODE 3: out_f32 = mulbuf * tanh(raw+bias)   (final output)
// INF32: main input is f32 (img), else bf16.
// ---------------------------------------------------------------------------
template<int MODE, int INF32>
__global__ __launch_bounds__(256) void mfma_gemm(
    const void* __restrict__ inA, const void* __restrict__ inB,
    const float* __restrict__ W, const float* __restrict__ bias,
    void* __restrict__ outp,
    float* __restrict__ s_sum, float* __restrict__ s_sq,
    const float* __restrict__ stA, const float* __restrict__ stA2,
    const float* __restrict__ stB, const float* __restrict__ stB2,
    const void* __restrict__ mulbuf)
{
    // SM: staging tile (16KB bf16 [64p][128c] swizzled)  then  C f32 [128][66]
    __shared__ __align__(16) unsigned char SM[33792];
    __shared__ float nrm[4][NCH];
    __shared__ float reds[256], redq[256];

    const int t    = threadIdx.x;
    const int lane = t & 63;
    const int wid  = t >> 6;
    const int b    = blockIdx.y;
    const int pblk = blockIdx.x * 64;
    const size_t bbase = (size_t)b * NCH * PSP;

    // ---- A fragments: wave's 32 o-rows, all K=128, straight from W --------
    bf16x8 afrag[2][4];
    {
        const int orow  = wid * 32 + (lane & 15);
        const int cbase = (lane >> 4) * 8;
        #pragma unroll
        for (int mt = 0; mt < 2; ++mt)
            #pragma unroll
            for (int kt = 0; kt < 4; ++kt) {
                const float* wp = W + (size_t)(orow + mt * 16) * NCH + kt * 32 + cbase;
                f32x4 w0 = *(const f32x4*)wp;
                f32x4 w1 = *(const f32x4*)(wp + 4);
                bf16x8 f;
                f[0]=f2bf(w0[0]); f[1]=f2bf(w0[1]); f[2]=f2bf(w0[2]); f[3]=f2bf(w0[3]);
                f[4]=f2bf(w1[0]); f[5]=f2bf(w1[1]); f[6]=f2bf(w1[2]); f[7]=f2bf(w1[3]);
                afrag[mt][kt] = f;
            }
    }

    if constexpr (MODE == 1) {
        if (t < NCH) {
            float m = stA[b * NCH + t] * (1.0f / PSP);
            float v = stA2[b * NCH + t] * (1.0f / PSP) - m * m;
            nrm[0][t] = m; nrm[1][t] = rsqrtf(v + EPSV);
        } else {
            int c = t - NCH;
            float m = stB[b * NCH + c] * (1.0f / PSP);
            float v = stB2[b * NCH + c] * (1.0f / PSP) - m * m;
            nrm[2][c] = m; nrm[3][c] = rsqrtf(v + EPSV);
        }
        __syncthreads();
    }

    // ---- stage input tile -> LDS [p][c] bf16, pair-packed, XOR-swizzled ----
    #pragma unroll
    for (int i = 0; i < 2; ++i) {
        const int u  = t + 256 * i;
        const int c2 = u >> 3;            // 0..63 -> channel pair
        const int p0 = (u & 7) * 8;       // 8 consecutive positions
        const int c  = c2 * 2;
        float va[8], vb[8];
        if constexpr (INF32) {
            const float* r0 = (const float*)inA + bbase + (size_t)c * PSP + pblk + p0;
            f32x4 a0 = *(const f32x4*)r0,         a1 = *(const f32x4*)(r0 + 4);
            f32x4 b0 = *(const f32x4*)(r0 + PSP), b1 = *(const f32x4*)(r0 + PSP + 4);
            va[0]=a0[0];va[1]=a0[1];va[2]=a0[2];va[3]=a0[3];
            va[4]=a1[0];va[5]=a1[1];va[6]=a1[2];va[7]=a1[3];
            vb[0]=b0[0];vb[1]=b0[1];vb[2]=b0[2];vb[3]=b0[3];
            vb[4]=b1[0];vb[5]=b1[1];vb[6]=b1[2];vb[7]=b1[3];
        } else {
            const short* r0 = (const short*)inA + bbase + (size_t)c * PSP + pblk + p0;
            bf16x8 a = *(const bf16x8*)r0;
            bf16x8 bb = *(const bf16x8*)(r0 + PSP);
            #pragma unroll
            for (int j = 0; j < 8; ++j) { va[j] = bf2f(a[j]); vb[j] = bf2f(bb[j]); }
        }
        if constexpr (MODE == 1) {
            const short* rB = (const short*)inB + bbase + (size_t)c * PSP + pblk + p0;
            bf16x8 w0 = *(const bf16x8*)rB;
            bf16x8 w1 = *(const bf16x8*)(rB + PSP);
            const float mA0 = nrm[0][c],   rA0 = nrm[1][c];
            const float mA1 = nrm[0][c+1], rA1 = nrm[1][c+1];
            const float mB0 = nrm[2][c],   rB0 = nrm[3][c];
            const float mB1 = nrm[2][c+1], rB1 = nrm[3][c+1];
            #pragma unroll
            for (int j = 0; j < 8; ++j) {
                va[j] = ((va[j] - mA0) * rA0) * ((bf2f(w0[j]) - mB0) * rB0);
                vb[j] = ((vb[j] - mA1) * rA1) * ((bf2f(w1[j]) - mB1) * rB1);
            }
        }
        #pragma unroll
        for (int j = 0; j < 8; ++j) {
            const int p = p0 + j;
            int byte = p * 256 + c2 * 4;
            byte ^= (((p & 7) ^ ((p >> 3) & 7)) << 4);
            uint32_t pk = (uint32_t)(uint16_t)f2bf(va[j])
                        | ((uint32_t)(uint16_t)f2bf(vb[j]) << 16);
            *(uint32_t*)(SM + byte) = pk;
        }
    }
    __syncthreads();

    // ---- MFMA: 32 per wave -------------------------------------------------
    f32x4 acc[2][4];
    #pragma unroll
    for (int mt = 0; mt < 2; ++mt)
        #pragma unroll
        for (int nt = 0; nt < 4; ++nt) acc[mt][nt] = (f32x4)0.0f;

    #pragma unroll
    for (int nt = 0; nt < 4; ++nt) {
        const int p  = nt * 16 + (lane & 15);
        const int cb = (lane >> 4) * 8;
        bf16x8 bfrag[4];
        #pragma unroll
        for (int kt = 0; kt < 4; ++kt) {
            int byte = p * 256 + (kt * 32 + cb) * 2;
            byte ^= (((p & 7) ^ ((p >> 3) & 7)) << 4);
            bfrag[kt] = *(const bf16x8*)(SM + byte);
        }
        #pragma unroll
        for (int kt = 0; kt < 4; ++kt) {
            acc[0][nt] = __builtin_amdgcn_mfma_f32_16x16x32_bf16(afrag[0][kt], bfrag[kt], acc[0][nt], 0, 0, 0);
            acc[1][nt] = __builtin_amdgcn_mfma_f32_16x16x32_bf16(afrag[1][kt], bfrag[kt], acc[1][nt], 0, 0, 0);
        }
    }
    __syncthreads();

    // ---- C -> LDS f32 [128][66] -------------------------------------------
    float* LC = (float*)SM;
    {
        const int pp = (lane & 15);
        const int og = wid * 32 + (lane >> 4) * 4;
        #pragma unroll
        for (int mt = 0; mt < 2; ++mt)
            #pragma unroll
            for (int nt = 0; nt < 4; ++nt) {
                f32x4 a = acc[mt][nt];
                const int o = og + mt * 16;
                const int p = nt * 16 + pp;
                #pragma unroll
                for (int r = 0; r < 4; ++r)
                    LC[(o + r) * 66 + p] = a[r];
            }
    }
    __syncthreads();

    // ---- epilogue: coalesced global stores + mode ops ---------------------
    {
        const int o  = t & 127;
        const int ph = (t >> 7) * 32;
        const float bia = bias[o];
        float vals[32];
        #pragma unroll
        for (int k = 0; k < 16; ++k) {
            f32x2 v = *(const f32x2*)&LC[o * 66 + ph + k * 2];
            vals[2*k]   = v[0] + bia;
            vals[2*k+1] = v[1] + bia;
        }
        if constexpr (MODE == 1 || MODE == 2) {
            #pragma unroll
            for (int j = 0; j < 32; ++j) vals[j] = fmaxf(vals[j], 0.0f);
        }
        if constexpr (MODE == 3) {
            const short* mp = (const short*)mulbuf + bbase + (size_t)o * PSP + pblk + ph;
            float* dst = (float*)outp + bbase + (size_t)o * PSP + pblk + ph;
            #pragma unroll
            for (int g = 0; g < 8; ++g) {
                f32x4 ov;
                #pragma unroll
                for (int j = 0; j < 4; ++j)
                    ov[j] = bf2f(mp[g*4+j]) * tanhf(vals[g*4+j]);
                *(f32x4*)(dst + g * 4) = ov;
            }
        } else {
            short* dst = (short*)outp + bbase + (size_t)o * PSP + pblk + ph;
            #pragma unroll
            for (int g = 0; g < 4; ++g) {
                bf16x8 s8;
                #pragma unroll
                for (int j = 0; j < 8; ++j) s8[j] = f2bf(vals[g*8+j]);
                *(bf16x8*)(dst + g * 8) = s8;
            }
        }
        if constexpr (MODE == 0) {
            float s = 0.0f, sq = 0.0f;
            #pragma unroll
            for (int j = 0; j < 32; ++j) { s += vals[j]; sq += vals[j] * vals[j]; }
            reds[t] = s; redq[t] = sq;
            __syncthreads();
            if (t < 128) {
                atomicAdd(&s_sum[b * NCH + t], reds[t] + reds[t + 128]);
                atomicAdd(&s_sq [b * NCH + t], redq[t] + redq[t + 128]);
            }
        }
    }
}

// ---------------------------------------------------------------------------
// Attention (bf16 q_pre in, bf16 x out in c-major-of-x_img == contiguous here)
// ---------------------------------------------------------------------------
__global__ __launch_bounds__(256) void attn_kernel(
    const short* __restrict__ q_pre, const float* __restrict__ kbuf,
    const float* __restrict__ vbuf, const float* __restrict__ qsum,
    const float* __restrict__ qsq, short* __restrict__ xout)
{
    __shared__ float mq[NCH], rq[NCH];
    const int t = threadIdx.x;
    const int b = blockIdx.y;
    if (t < NCH) {
        float m = qsum[b * NCH + t] * (1.0f / PSP);
        float v = qsq[b * NCH + t] * (1.0f / PSP) - m * m;
        mq[t] = m;
        rq[t] = rsqrtf(v + EPSV) * 0.25f;   // fold attention scale
    }
    __syncthreads();

    const int p = blockIdx.x * 256 + t;
    const short* qb = q_pre + (size_t)b * NCH * PSP + p;
    const float* kb = kbuf + b * (NCH * 20);
    const float* vb = vbuf + b * (NCH * 20);
    short* xb = xout + (size_t)b * NCH * PSP + (size_t)p * NCH;

    #pragma unroll 1
    for (int h = 0; h < 8; ++h) {
        float qn[16];
        #pragma unroll
        for (int j = 0; j < 16; ++j) {
            int c = h * 16 + j;
            qn[j] = (bf2f(qb[(size_t)c * PSP]) - mq[c]) * rq[c];
        }
        float sim[20];
        #pragma unroll
        for (int l = 0; l < 20; ++l) sim[l] = 0.0f;
        #pragma unroll
        for (int j = 0; j < 16; ++j) {
            const int c = h * 16 + j;
            #pragma unroll
            for (int l = 0; l < 20; ++l)
                sim[l] = fmaf(qn[j], kb[c * 20 + l], sim[l]);
        }
        float mx = sim[0];
        #pragma unroll
        for (int l = 1; l < 20; ++l) mx = fmaxf(mx, sim[l]);
        float se = 0.0f;
        #pragma unroll
        for (int l = 0; l < 20; ++l) {
            float e = __expf(sim[l] - mx);
            sim[l] = e; se += e;
        }
        float inv = 1.0f / se;
        float x[16];
        #pragma unroll
        for (int j = 0; j < 16; ++j) {
            int c = h * 16 + j;
            float a = 0.0f;
            #pragma unroll
            for (int l = 0; l < 20; ++l)
                a = fmaf(sim[l], vb[c * 20 + l], a);
            x[j] = a * inv;
        }
        bf16x8 s0, s1;
        #pragma unroll
        for (int j = 0; j < 8; ++j) { s0[j] = f2bf(x[j]); s1[j] = f2bf(x[8+j]); }
        *(bf16x8*)(xb + h * 16)     = s0;
        *(bf16x8*)(xb + h * 16 + 8) = s1;
    }
}

// ---------------------------------------------------------------------------
extern "C" void kernel_launch(void* const* d_in, const int* in_sizes, int n_in,
                              void* d_out, int out_size, void* d_ws, size_t ws_size,
                              hipStream_t stream)
{
    const float* img  = (const float*)d_in[0];
    const float* lang = (const float*)d_in[1];
    const float* Wq   = (const float*)d_in[2];
    const float* bq   = (const float*)d_in[3];
    const float* Wk   = (const float*)d_in[4];
    const float* bk   = (const float*)d_in[5];
    const float* Wv   = (const float*)d_in[6];
    const float* bv   = (const float*)d_in[7];
    const float* Wpw  = (const float*)d_in[8];
    const float* bpw  = (const float*)d_in[9];
    const float* Wpi  = (const float*)d_in[10];
    const float* bpi  = (const float*)d_in[11];
    const float* Wpo  = (const float*)d_in[12];
    const float* bpo  = (const float*)d_in[13];
    const float* Wg1  = (const float*)d_in[14];
    const float* bg1  = (const float*)d_in[15];
    const float* Wg2  = (const float*)d_in[16];
    const float* bg2  = (const float*)d_in[17];
    float* outp = (float*)d_out;

    const size_t N = (size_t)NB * NCH * PSP;   // elements per intermediate
    // ws: bufA/B/C bf16[N], kbuf/vbuf f32, stats f32[6*256]
    const size_t needed = 3 * N * sizeof(short) + (2 * 2560 * 2 + 6 * 256) * sizeof(float);
    if (ws_size < needed) return;

    short* bufA = (short*)d_ws;
    short* bufB = bufA + N;
    short* bufC = bufB + N;
    float* kbuf = (float*)(bufC + N);
    float* vbuf = kbuf + 2 * 2560;
    float* st   = vbuf + 2 * 2560;
    float* qs   = st;            // q sum / sumsq
    float* qs2  = st + 256;
    float* ss   = st + 512;      // skip sum / sumsq
    float* ss2  = st + 768;
    float* wsu  = st + 1024;     // weight sum / sumsq
    float* ws2  = st + 1280;

    hipMemsetAsync(st, 0, 6 * 256 * sizeof(float), stream);
    kv_kernel<<<dim3(40), dim3(256), 0, stream>>>(lang, Wk, bk, Wv, bv, kbuf, vbuf);

    const dim3 gg(PSP / 64, NB), gb(256);

    // G1: q_pre = Wq*img (+stats) -> bufA (bf16)
    mfma_gemm<0, 1><<<gg, gb, 0, stream>>>(img, nullptr, Wq, bq, bufA,
                                           qs, qs2, nullptr, nullptr, nullptr, nullptr, nullptr);
    // attention: bufA -> bufB (x_img c-major)
    attn_kernel<<<dim3(PSP / 256, NB), gb, 0, stream>>>(bufA, kbuf, vbuf, qs, qs2, bufB);
    // G2: skip_pre = Wpi*img (+stats) -> bufC
    mfma_gemm<0, 1><<<gg, gb, 0, stream>>>(img, nullptr, Wpi, bpi, bufC,
                                           ss, ss2, nullptr, nullptr, nullptr, nullptr, nullptr);
    // G3: weight_pre = Wpw*x_img (+stats) -> bufA (q_pre dead after attn)
    mfma_gemm<0, 0><<<gg, gb, 0, stream>>>(bufB, nullptr, Wpw, bpw, bufA,
                                           wsu, ws2, nullptr, nullptr, nullptr, nullptr, nullptr);
    // G4: out = relu(Wpo*(norm(skip)*norm(weight))) -> bufB (x dead)
    mfma_gemm<1, 0><<<gg, gb, 0, stream>>>(bufC, bufA, Wpo, bpo, bufB,
                                           nullptr, nullptr, ss, ss2, wsu, ws2, nullptr);
    // G5: relu1 = relu(Wg1*out) -> bufA
    mfma_gemm<2, 0><<<gg, gb, 0, stream>>>(bufB, nullptr, Wg1, bg1, bufA,
                                           nullptr, nullptr, nullptr, nullptr, nullptr, nullptr, nullptr);
    // G6: final = out * tanh(Wg2*relu1) -> d_out (f32)
    mfma_gemm<3, 0><<<gg, gb, 0, stream>>>(bufA, nullptr, Wg2, bg2, outp,
                                           nullptr, nullptr, nullptr, nullptr, nullptr, nullptr, bufB);
}

// Round 4
// 451.194 us; speedup vs baseline: 2.8697x; 1.4217x over previous
//
#include <hip/hip_runtime.h>
#include <cstdint>
#include <cstddef>

#define PSP 110592          // 48*48*48 positions per batch
#define NCH 128
#define NB  2
#define CPW 66              // u32 stride of CP-layout rows (64 + 2 pad)
static constexpr float EPSV = 1e-5f;

typedef short bf16x8 __attribute__((ext_vector_type(8)));
typedef float f32x4  __attribute__((ext_vector_type(4)));
typedef float f32x2  __attribute__((ext_vector_type(2)));

static __device__ __forceinline__ short f2bf(float f) {
    uint32_t u = __builtin_bit_cast(uint32_t, f);
    u += 0x7FFF + ((u >> 16) & 1);          // RNE
    return (short)(u >> 16);
}
static __device__ __forceinline__ float bf2f(short s) {
    uint32_t u = ((uint32_t)(uint16_t)s) << 16;
    return __builtin_bit_cast(float, u);
}
static __device__ __forceinline__ uint32_t pk2f(float lo, float hi) {
    return (uint32_t)(uint16_t)f2bf(lo) | ((uint32_t)(uint16_t)f2bf(hi) << 16);
}
static __device__ __forceinline__ uint32_t pk2s(short lo, short hi) {
    return (uint32_t)(uint16_t)lo | ((uint32_t)(uint16_t)hi << 16);
}

// ---------------------------------------------------------------------------
// k/v projections (tiny, f32 out)
// ---------------------------------------------------------------------------
__global__ __launch_bounds__(256) void kv_kernel(
    const float* __restrict__ lang,
    const float* __restrict__ Wk, const float* __restrict__ bk,
    const float* __restrict__ Wv, const float* __restrict__ bv,
    float* __restrict__ kout, float* __restrict__ vout)
{
    int gid = blockIdx.x * 256 + threadIdx.x;     // 0..10239
    int sel = gid / 5120;
    int r   = gid % 5120;
    int b   = r / 2560;
    int o   = (r % 2560) / 20;
    int l   = r % 20;
    const float* W  = sel ? Wv : Wk;
    const float* bb = sel ? bv : bk;
    const float* lg = lang + b * 256 * 20 + l;
    float acc = bb[o];
    #pragma unroll 8
    for (int c = 0; c < 256; ++c)
        acc = fmaf(W[o * 256 + c], lg[c * 20], acc);
    (sel ? vout : kout)[b * 2560 + o * 20 + l] = acc;
}

// ---------------------------------------------------------------------------
// shared device helpers
// ---------------------------------------------------------------------------
// stage a 128c x 64p tile into CP layout (u32[c2*CPW + p] = pair(c=2c2, 2c2+1))
template<int F32>
static __device__ __forceinline__ void stage_plain(uint32_t* CP, const void* src)
{
    const int t = threadIdx.x, c2 = t >> 2, p0 = (t & 3) * 16;
    const size_t ro = (size_t)(2 * c2) * PSP + p0;
    uint32_t w[16];
    if constexpr (F32) {
        const float* s0 = (const float*)src + ro;
        #pragma unroll
        for (int i = 0; i < 4; ++i) {
            f32x4 a = *(const f32x4*)(s0 + i * 4);
            f32x4 b = *(const f32x4*)(s0 + PSP + i * 4);
            #pragma unroll
            for (int j = 0; j < 4; ++j) w[i * 4 + j] = pk2f(a[j], b[j]);
        }
    } else {
        const short* s0 = (const short*)src + ro;
        bf16x8 a0 = *(const bf16x8*)s0,         a1 = *(const bf16x8*)(s0 + 8);
        bf16x8 b0 = *(const bf16x8*)(s0 + PSP), b1 = *(const bf16x8*)(s0 + PSP + 8);
        #pragma unroll
        for (int k = 0; k < 8; ++k) { w[k] = pk2s(a0[k], b0[k]); w[8 + k] = pk2s(a1[k], b1[k]); }
    }
    uint32_t* base = CP + c2 * CPW + p0;
    #pragma unroll
    for (int k = 0; k < 8; ++k)
        *(uint2*)(base + 2 * k) = make_uint2(w[2 * k], w[2 * k + 1]);
}

static __device__ __forceinline__ bf16x8 read_bfrag(const uint32_t* CP, int c2b, int p)
{
    union { uint32_t u[4]; bf16x8 f; } cv;
    #pragma unroll
    for (int i = 0; i < 4; ++i) cv.u[i] = CP[(c2b + i) * CPW + p];
    return cv.f;
}

static __device__ __forceinline__ void load_afrag(const float* __restrict__ W,
                                                  int wid, int lane, bf16x8 af[2][4])
{
    const int orow = wid * 32 + (lane & 15);
    const int cb   = (lane >> 4) * 8;
    #pragma unroll
    for (int mt = 0; mt < 2; ++mt)
        #pragma unroll
        for (int kt = 0; kt < 4; ++kt) {
            const float* wp = W + (size_t)(orow + mt * 16) * NCH + kt * 32 + cb;
            f32x4 w0 = *(const f32x4*)wp;
            f32x4 w1 = *(const f32x4*)(wp + 4);
            bf16x8 f;
            f[0]=f2bf(w0[0]); f[1]=f2bf(w0[1]); f[2]=f2bf(w0[2]); f[3]=f2bf(w0[3]);
            f[4]=f2bf(w1[0]); f[5]=f2bf(w1[1]); f[6]=f2bf(w1[2]); f[7]=f2bf(w1[3]);
            af[mt][kt] = f;
        }
}

static __device__ __forceinline__ void run_mfma(const uint32_t* CP, const bf16x8 af[2][4],
                                                f32x4 acc[2][4], int lane)
{
    const int l15 = lane & 15, kh = lane >> 4;
    #pragma unroll
    for (int nt = 0; nt < 4; ++nt) {
        const int p = nt * 16 + l15;
        bf16x8 bf[4];
        #pragma unroll
        for (int kt = 0; kt < 4; ++kt) bf[kt] = read_bfrag(CP, kt * 16 + kh * 4, p);
        #pragma unroll
        for (int kt = 0; kt < 4; ++kt) {
            acc[0][nt] = __builtin_amdgcn_mfma_f32_16x16x32_bf16(af[0][kt], bf[kt], acc[0][nt], 0, 0, 0);
            acc[1][nt] = __builtin_amdgcn_mfma_f32_16x16x32_bf16(af[1][kt], bf[kt], acc[1][nt], 0, 0, 0);
        }
    }
}

static __device__ __forceinline__ void write_LC(float* LC, const f32x4 acc[2][4],
                                                int wid, int lane)
{
    const int l15 = lane & 15, og = wid * 32 + (lane >> 4) * 4;
    #pragma unroll
    for (int mt = 0; mt < 2; ++mt)
        #pragma unroll
        for (int nt = 0; nt < 4; ++nt) {
            const int o = og + mt * 16, p = nt * 16 + l15;
            #pragma unroll
            for (int r = 0; r < 4; ++r) LC[(o + r) * CPW + p] = acc[mt][nt][r];
        }
}

// epilogue: bias (+relu) -> bf16 store, fully-coalesced (8 lanes = one 128B line)
// optional per-(b,o) sum/sumsq atomics (stats ptrs pre-offset by b*NCH).
static __device__ __forceinline__ void epi_bf16(const float* LC, const float* __restrict__ bias,
        short* __restrict__ dst, bool relu, bool stats,
        float* __restrict__ s_sum, float* __restrict__ s_sq,
        float* sredS, float* sredQ)
{
    const int t = threadIdx.x;
    float rs[4], rq[4];
    #pragma unroll
    for (int r = 0; r < 4; ++r) {
        const int u = r * 256 + t, o = u >> 3, ch = u & 7;
        const float bia = bias[o];
        float v[8];
        #pragma unroll
        for (int j = 0; j < 4; ++j) {
            f32x2 w = *(const f32x2*)&LC[o * CPW + ch * 8 + j * 2];
            v[2 * j]     = w[0] + bia;
            v[2 * j + 1] = w[1] + bia;
        }
        if (relu) {
            #pragma unroll
            for (int j = 0; j < 8; ++j) v[j] = fmaxf(v[j], 0.0f);
        }
        bf16x8 s8;
        #pragma unroll
        for (int j = 0; j < 8; ++j) s8[j] = f2bf(v[j]);
        *(bf16x8*)(dst + (size_t)o * PSP + ch * 8) = s8;
        if (stats) {
            float s = 0.0f, q = 0.0f;
            #pragma unroll
            for (int j = 0; j < 8; ++j) { s += v[j]; q += v[j] * v[j]; }
            s += __shfl_xor(s, 1); q += __shfl_xor(q, 1);
            s += __shfl_xor(s, 2); q += __shfl_xor(q, 2);
            s += __shfl_xor(s, 4); q += __shfl_xor(q, 4);
            rs[r] = s; rq[r] = q;
        }
    }
    if (stats) {
        if ((t & 7) == 0) {
            #pragma unroll
            for (int r = 0; r < 4; ++r) {
                sredS[r * 32 + (t >> 3)] = rs[r];
                sredQ[r * 32 + (t >> 3)] = rq[r];
            }
        }
        __syncthreads();
        if (t < 128) {
            atomicAdd(&s_sum[t], sredS[t]);
            atomicAdd(&s_sq[t],  sredQ[t]);
        }
    }
}

// ---------------------------------------------------------------------------
// G12: q_pre = Wq*img (+stats) and skip_pre = Wpi*img (+stats); img read once.
// ---------------------------------------------------------------------------
__global__ __launch_bounds__(256) void g12_kernel(
    const float* __restrict__ img,
    const float* __restrict__ Wq, const float* __restrict__ bq,
    const float* __restrict__ Wpi, const float* __restrict__ bpi,
    short* __restrict__ qout, short* __restrict__ sout,
    float* __restrict__ qs, float* __restrict__ qs2,
    float* __restrict__ ss, float* __restrict__ ss2)
{
    __shared__ __align__(16) unsigned char SMEM[16896 + 33792];
    __shared__ float sredS[128], sredQ[128];
    uint32_t* STG = (uint32_t*)SMEM;
    float*    LC  = (float*)(SMEM + 16896);

    const int t = threadIdx.x, lane = t & 63, wid = t >> 6;
    const int b = blockIdx.y;
    const size_t bbase = (size_t)b * NCH * PSP;
    const int pblk = blockIdx.x * 64;

    stage_plain<1>(STG, img + bbase + pblk);

    bf16x8 af[2][4];
    load_afrag(Wq, wid, lane, af);
    __syncthreads();

    f32x4 acc[2][4];
    #pragma unroll
    for (int m = 0; m < 2; ++m)
        #pragma unroll
        for (int n = 0; n < 4; ++n) acc[m][n] = (f32x4)0.0f;
    run_mfma(STG, af, acc, lane);
    __syncthreads();
    write_LC(LC, acc, wid, lane);
    __syncthreads();
    epi_bf16(LC, bq, qout + bbase + pblk, false, true,
             qs + b * NCH, qs2 + b * NCH, sredS, sredQ);

    // second GEMM, reusing staged tile
    load_afrag(Wpi, wid, lane, af);
    #pragma unroll
    for (int m = 0; m < 2; ++m)
        #pragma unroll
        for (int n = 0; n < 4; ++n) acc[m][n] = (f32x4)0.0f;
    run_mfma(STG, af, acc, lane);
    __syncthreads();
    write_LC(LC, acc, wid, lane);
    __syncthreads();
    epi_bf16(LC, bpi, sout + bbase + pblk, false, true,
             ss + b * NCH, ss2 + b * NCH, sredS, sredQ);
}

// ---------------------------------------------------------------------------
// Attention (round-2 proven version): bf16 q_pre c-major in, x written
// position-major flat (b,p,c) == x_img channel-major (raw reshape semantics).
// ---------------------------------------------------------------------------
__global__ __launch_bounds__(256) void attn_kernel(
    const short* __restrict__ q_pre, const float* __restrict__ kbuf,
    const float* __restrict__ vbuf, const float* __restrict__ qsum,
    const float* __restrict__ qsq, short* __restrict__ xout)
{
    __shared__ float mq[NCH], rq[NCH];
    const int t = threadIdx.x;
    const int b = blockIdx.y;
    if (t < NCH) {
        float m = qsum[b * NCH + t] * (1.0f / PSP);
        float v = qsq[b * NCH + t] * (1.0f / PSP) - m * m;
        mq[t] = m;
        rq[t] = rsqrtf(v + EPSV) * 0.25f;   // fold attention scale
    }
    __syncthreads();

    const int p = blockIdx.x * 256 + t;
    const short* qb = q_pre + (size_t)b * NCH * PSP + p;
    const float* kb = kbuf + b * (NCH * 20);
    const float* vb = vbuf + b * (NCH * 20);
    short* xb = xout + (size_t)b * NCH * PSP + (size_t)p * NCH;

    #pragma unroll 1
    for (int h = 0; h < 8; ++h) {
        float qn[16];
        #pragma unroll
        for (int j = 0; j < 16; ++j) {
            int c = h * 16 + j;
            qn[j] = (bf2f(qb[(size_t)c * PSP]) - mq[c]) * rq[c];
        }
        float sim[20];
        #pragma unroll
        for (int l = 0; l < 20; ++l) sim[l] = 0.0f;
        #pragma unroll
        for (int j = 0; j < 16; ++j) {
            const int c = h * 16 + j;
            #pragma unroll
            for (int l = 0; l < 20; ++l)
                sim[l] = fmaf(qn[j], kb[c * 20 + l], sim[l]);
        }
        float mx = sim[0];
        #pragma unroll
        for (int l = 1; l < 20; ++l) mx = fmaxf(mx, sim[l]);
        float se = 0.0f;
        #pragma unroll
        for (int l = 0; l < 20; ++l) {
            float e = __expf(sim[l] - mx);
            sim[l] = e; se += e;
        }
        float inv = 1.0f / se;
        float x[16];
        #pragma unroll
        for (int j = 0; j < 16; ++j) {
            int c = h * 16 + j;
            float a = 0.0f;
            #pragma unroll
            for (int l = 0; l < 20; ++l)
                a = fmaf(sim[l], vb[c * 20 + l], a);
            x[j] = a * inv;
        }
        bf16x8 s0, s1;
        #pragma unroll
        for (int j = 0; j < 8; ++j) { s0[j] = f2bf(x[j]); s1[j] = f2bf(x[8+j]); }
        *(bf16x8*)(xb + h * 16)     = s0;
        *(bf16x8*)(xb + h * 16 + 8) = s1;
    }
}

// ---------------------------------------------------------------------------
// G3: weight_pre = Wpw * x_img (+stats); x read c-major (flat reinterpret)
// ---------------------------------------------------------------------------
__global__ __launch_bounds__(256) void g3_kernel(
    const short* __restrict__ x,
    const float* __restrict__ Wpw, const float* __restrict__ bpw,
    short* __restrict__ wout,
    float* __restrict__ wsu, float* __restrict__ ws2)
{
    __shared__ __align__(16) unsigned char SMEM[33792];
    __shared__ float sredS[128], sredQ[128];
    uint32_t* STG = (uint32_t*)SMEM;
    float*    LC  = (float*)SMEM;    // overlaps (post-MFMA)

    const int t = threadIdx.x, lane = t & 63, wid = t >> 6;
    const int b = blockIdx.y;
    const size_t bbase = (size_t)b * NCH * PSP;
    const int pblk = blockIdx.x * 64;

    stage_plain<0>(STG, x + bbase + pblk);

    bf16x8 af[2][4];
    load_afrag(Wpw, wid, lane, af);
    __syncthreads();

    f32x4 acc[2][4];
    #pragma unroll
    for (int m = 0; m < 2; ++m)
        #pragma unroll
        for (int n = 0; n < 4; ++n) acc[m][n] = (f32x4)0.0f;
    run_mfma(STG, af, acc, lane);
    __syncthreads();
    write_LC(LC, acc, wid, lane);
    __syncthreads();
    epi_bf16(LC, bpw, wout + bbase + pblk, false, true,
             wsu + b * NCH, ws2 + b * NCH, sredS, sredQ);
}

// ---------------------------------------------------------------------------
// G4: out = relu(Wpo * (norm(skip)*norm(weight)))
// ---------------------------------------------------------------------------
__global__ __launch_bounds__(256) void g4_kernel(
    const short* __restrict__ skip, const short* __restrict__ wgt,
    const float* __restrict__ sA, const float* __restrict__ sA2,
    const float* __restrict__ sB, const float* __restrict__ sB2,
    const float* __restrict__ Wpo, const float* __restrict__ bpo,
    short* __restrict__ outp)
{
    __shared__ __align__(16) unsigned char SMEM[33792];
    __shared__ float nm[4][NCH];
    uint32_t* STG = (uint32_t*)SMEM;
    float*    LC  = (float*)SMEM;    // overlaps (post-MFMA)

    const int t = threadIdx.x, lane = t & 63, wid = t >> 6;
    const int b = blockIdx.y;
    const size_t bbase = (size_t)b * NCH * PSP;
    const int pblk = blockIdx.x * 64;

    if (t < NCH) {
        float m = sA[b * NCH + t] * (1.0f / PSP);
        float v = sA2[b * NCH + t] * (1.0f / PSP) - m * m;
        nm[0][t] = m; nm[1][t] = rsqrtf(v + EPSV);
    } else {
        int c = t - NCH;
        float m = sB[b * NCH + c] * (1.0f / PSP);
        float v = sB2[b * NCH + c] * (1.0f / PSP) - m * m;
        nm[2][c] = m; nm[3][c] = rsqrtf(v + EPSV);
    }
    __syncthreads();

    // stage norm(skip)*norm(weight) -> STG
    {
        const int c2 = t >> 2, p0 = (t & 3) * 16, c = 2 * c2;
        const short* s0 = skip + bbase + (size_t)c * PSP + pblk + p0;
        const short* g0 = wgt  + bbase + (size_t)c * PSP + pblk + p0;
        bf16x8 a0 = *(const bf16x8*)s0,         a1 = *(const bf16x8*)(s0 + 8);
        bf16x8 b0 = *(const bf16x8*)(s0 + PSP), b1 = *(const bf16x8*)(s0 + PSP + 8);
        bf16x8 c0 = *(const bf16x8*)g0,         c1 = *(const bf16x8*)(g0 + 8);
        bf16x8 d0 = *(const bf16x8*)(g0 + PSP), d1 = *(const bf16x8*)(g0 + PSP + 8);
        const float mA0 = nm[0][c], rA0 = nm[1][c], mA1 = nm[0][c+1], rA1 = nm[1][c+1];
        const float mB0 = nm[2][c], rB0 = nm[3][c], mB1 = nm[2][c+1], rB1 = nm[3][c+1];
        uint32_t w[16];
        #pragma unroll
        for (int k = 0; k < 8; ++k) {
            float lo  = ((bf2f(a0[k]) - mA0) * rA0) * ((bf2f(c0[k]) - mB0) * rB0);
            float hi  = ((bf2f(b0[k]) - mA1) * rA1) * ((bf2f(d0[k]) - mB1) * rB1);
            float lo2 = ((bf2f(a1[k]) - mA0) * rA0) * ((bf2f(c1[k]) - mB0) * rB0);
            float hi2 = ((bf2f(b1[k]) - mA1) * rA1) * ((bf2f(d1[k]) - mB1) * rB1);
            w[k] = pk2f(lo, hi); w[8 + k] = pk2f(lo2, hi2);
        }
        uint32_t* base = STG + c2 * CPW + p0;
        #pragma unroll
        for (int k = 0; k < 8; ++k)
            *(uint2*)(base + 2 * k) = make_uint2(w[2 * k], w[2 * k + 1]);
    }

    bf16x8 af[2][4];
    load_afrag(Wpo, wid, lane, af);
    __syncthreads();

    f32x4 acc[2][4];
    #pragma unroll
    for (int m = 0; m < 2; ++m)
        #pragma unroll
        for (int n = 0; n < 4; ++n) acc[m][n] = (f32x4)0.0f;
    run_mfma(STG, af, acc, lane);
    __syncthreads();
    write_LC(LC, acc, wid, lane);
    __syncthreads();
    epi_bf16(LC, bpo, outp + bbase + pblk, true, false,
             nullptr, nullptr, nullptr, nullptr);
}

// ---------------------------------------------------------------------------
// G56: final = out * tanh(Wg2 * relu(Wg1*out + bg1) + bg2); relu1 stays in LDS
// ---------------------------------------------------------------------------
__global__ __launch_bounds__(256) void g56_kernel(
    const short* __restrict__ outb,
    const float* __restrict__ Wg1, const float* __restrict__ bg1,
    const float* __restrict__ Wg2, const float* __restrict__ bg2,
    float* __restrict__ fin)
{
    __shared__ __align__(16) unsigned char SMEM[16896 + 33792];
    uint32_t* STG = (uint32_t*)SMEM;             // 'out' tile, alive to the end
    uint32_t* RT  = (uint32_t*)(SMEM + 16896);   // relu1 tile
    float*    LC  = (float*)(SMEM + 16896);      // overlaps RT (post-MFMA2)

    const int t = threadIdx.x, lane = t & 63, wid = t >> 6;
    const int b = blockIdx.y;
    const size_t bbase = (size_t)b * NCH * PSP;
    const int pblk = blockIdx.x * 64;

    stage_plain<0>(STG, outb + bbase + pblk);

    bf16x8 af[2][4];
    load_afrag(Wg1, wid, lane, af);

    float bg1v[2][4];
    {
        const int og = wid * 32 + (lane >> 4) * 4;
        #pragma unroll
        for (int mt = 0; mt < 2; ++mt)
            #pragma unroll
            for (int r = 0; r < 4; ++r) bg1v[mt][r] = bg1[og + mt * 16 + r];
    }
    __syncthreads();

    f32x4 acc[2][4];
    #pragma unroll
    for (int m = 0; m < 2; ++m)
        #pragma unroll
        for (int n = 0; n < 4; ++n) acc[m][n] = (f32x4)0.0f;
    run_mfma(STG, af, acc, lane);

    // relu1 -> RT (bf16 pairs); lane holds 4 consecutive o at fixed p
    {
        const int l15 = lane & 15, og = wid * 32 + (lane >> 4) * 4;
        #pragma unroll
        for (int mt = 0; mt < 2; ++mt)
            #pragma unroll
            for (int nt = 0; nt < 4; ++nt) {
                const int o = og + mt * 16, p = nt * 16 + l15;
                f32x4 a = acc[mt][nt];
                float z0 = fmaxf(a[0] + bg1v[mt][0], 0.0f);
                float z1 = fmaxf(a[1] + bg1v[mt][1], 0.0f);
                float z2 = fmaxf(a[2] + bg1v[mt][2], 0.0f);
                float z3 = fmaxf(a[3] + bg1v[mt][3], 0.0f);
                RT[((o >> 1) + 0) * CPW + p] = pk2f(z0, z1);
                RT[((o >> 1) + 1) * CPW + p] = pk2f(z2, z3);
            }
    }
    load_afrag(Wg2, wid, lane, af);
    __syncthreads();

    #pragma unroll
    for (int m = 0; m < 2; ++m)
        #pragma unroll
        for (int n = 0; n < 4; ++n) acc[m][n] = (f32x4)0.0f;
    run_mfma(RT, af, acc, lane);
    __syncthreads();                 // RT reads done; LC may overwrite
    write_LC(LC, acc, wid, lane);
    __syncthreads();

    // epilogue: f32 out = stage * tanh(LC + bg2), coalesced 16B/lane
    {
        float* dst = fin + bbase + pblk;
        #pragma unroll
        for (int r = 0; r < 8; ++r) {
            const int u = r * 256 + t, o = u >> 4, ch = u & 15;
            const float bia = bg2[o];
            f32x2 v0 = *(const f32x2*)&LC[o * CPW + ch * 4];
            f32x2 v1 = *(const f32x2*)&LC[o * CPW + ch * 4 + 2];
            uint2 m01 = *(const uint2*)&STG[(o >> 1) * CPW + ch * 4];
            uint2 m23 = *(const uint2*)&STG[(o >> 1) * CPW + ch * 4 + 2];
            const int hi = o & 1;
            float m[4];
            m[0] = bf2f((short)(hi ? (m01.x >> 16) : (m01.x & 0xffff)));
            m[1] = bf2f((short)(hi ? (m01.y >> 16) : (m01.y & 0xffff)));
            m[2] = bf2f((short)(hi ? (m23.x >> 16) : (m23.x & 0xffff)));
            m[3] = bf2f((short)(hi ? (m23.y >> 16) : (m23.y & 0xffff)));
            f32x4 ov;
            ov[0] = m[0] * tanhf(v0[0] + bia);
            ov[1] = m[1] * tanhf(v0[1] + bia);
            ov[2] = m[2] * tanhf(v1[0] + bia);
            ov[3] = m[3] * tanhf(v1[1] + bia);
            *(f32x4*)(dst + (size_t)o * PSP + ch * 4) = ov;
        }
    }
}

// ---------------------------------------------------------------------------
extern "C" void kernel_launch(void* const* d_in, const int* in_sizes, int n_in,
                              void* d_out, int out_size, void* d_ws, size_t ws_size,
                              hipStream_t stream)
{
    const float* img  = (const float*)d_in[0];
    const float* lang = (const float*)d_in[1];
    const float* Wq   = (const float*)d_in[2];
    const float* bq   = (const float*)d_in[3];
    const float* Wk   = (const float*)d_in[4];
    const float* bk   = (const float*)d_in[5];
    const float* Wv   = (const float*)d_in[6];
    const float* bv   = (const float*)d_in[7];
    const float* Wpw  = (const float*)d_in[8];
    const float* bpw  = (const float*)d_in[9];
    const float* Wpi  = (const float*)d_in[10];
    const float* bpi  = (const float*)d_in[11];
    const float* Wpo  = (const float*)d_in[12];
    const float* bpo  = (const float*)d_in[13];
    const float* Wg1  = (const float*)d_in[14];
    const float* bg1  = (const float*)d_in[15];
    const float* Wg2  = (const float*)d_in[16];
    const float* bg2  = (const float*)d_in[17];
    float* outp = (float*)d_out;

    const size_t N = (size_t)NB * NCH * PSP;
    const size_t needed = 3 * N * sizeof(short) + (2 * 2560 * 2 + 6 * 256) * sizeof(float);
    if (ws_size < needed) return;

    short* bufA = (short*)d_ws;          // q_pre, then weight_pre
    short* bufB = bufA + N;              // x, then 'out'
    short* bufC = bufB + N;              // skip_pre
    float* kbuf = (float*)(bufC + N);
    float* vbuf = kbuf + 2 * 2560;
    float* st   = vbuf + 2 * 2560;
    float* qs   = st;
    float* qs2  = st + 256;
    float* ss   = st + 512;
    float* ss2  = st + 768;
    float* wsu  = st + 1024;
    float* ws2  = st + 1280;

    hipMemsetAsync(st, 0, 6 * 256 * sizeof(float), stream);
    kv_kernel<<<dim3(40), dim3(256), 0, stream>>>(lang, Wk, bk, Wv, bv, kbuf, vbuf);

    const dim3 gg(PSP / 64, NB), gb(256);

    // q_pre -> bufA, skip_pre -> bufC (img read once)
    g12_kernel<<<gg, gb, 0, stream>>>(img, Wq, bq, Wpi, bpi, bufA, bufC,
                                      qs, qs2, ss, ss2);
    // attention: q_pre -> x (bufB), flat (b,p,c) order == x_img c-major
    attn_kernel<<<dim3(PSP / 256, NB), gb, 0, stream>>>(bufA, kbuf, vbuf, qs, qs2, bufB);
    // weight_pre = Wpw * x_img (+stats) -> bufA (q_pre dead)
    g3_kernel<<<gg, gb, 0, stream>>>(bufB, Wpw, bpw, bufA, wsu, ws2);
    // out = relu(Wpo*(norm(skip)*norm(weight))) -> bufB (x dead)
    g4_kernel<<<gg, gb, 0, stream>>>(bufC, bufA, ss, ss2, wsu, ws2,
                                     Wpo, bpo, bufB);
    // final -> d_out
    g56_kernel<<<gg, gb, 0, stream>>>(bufB, Wg1, bg1, Wg2, bg2, outp);
}

// Round 6
// 419.216 us; speedup vs baseline: 3.0886x; 1.0763x over previous
//
#include <hip/hip_runtime.h>
#include <cstdint>
#include <cstddef>

#define PSP 110592          // 48*48*48 positions per batch
#define NCH 128
#define NB  2
#define CPW 66              // u32 stride of CP-layout rows (64 + 2 pad)
#define TPB 4               // 64-pos tiles per GEMM block
static constexpr float EPSV = 1e-5f;

typedef short bf16x8 __attribute__((ext_vector_type(8)));
typedef float f32x4  __attribute__((ext_vector_type(4)));

static __device__ __forceinline__ short f2bf(float f) {
    uint32_t u = __builtin_bit_cast(uint32_t, f);
    u += 0x7FFF + ((u >> 16) & 1);          // RNE
    return (short)(u >> 16);
}
static __device__ __forceinline__ float bf2f(short s) {
    uint32_t u = ((uint32_t)(uint16_t)s) << 16;
    return __builtin_bit_cast(float, u);
}
static __device__ __forceinline__ float bfLO(uint32_t w) { return bf2f((short)(w & 0xffff)); }
static __device__ __forceinline__ float bfHI(uint32_t w) { return bf2f((short)(w >> 16)); }
static __device__ __forceinline__ uint32_t pk2f(float lo, float hi) {
    return (uint32_t)(uint16_t)f2bf(lo) | ((uint32_t)(uint16_t)f2bf(hi) << 16);
}
static __device__ __forceinline__ uint32_t pk2s(short lo, short hi) {
    return (uint32_t)(uint16_t)lo | ((uint32_t)(uint16_t)hi << 16);
}

// ---------------------------------------------------------------------------
// tiny kernels
// ---------------------------------------------------------------------------
__global__ __launch_bounds__(256) void kv_kernel(
    const float* __restrict__ lang,
    const float* __restrict__ Wk, const float* __restrict__ bk,
    const float* __restrict__ Wv, const float* __restrict__ bv,
    float* __restrict__ kout, float* __restrict__ vout)
{
    int gid = blockIdx.x * 256 + threadIdx.x;     // 0..10239
    int sel = gid / 5120;
    int r   = gid % 5120;
    int b   = r / 2560;
    int o   = (r % 2560) / 20;
    int l   = r % 20;
    const float* W  = sel ? Wv : Wk;
    const float* bb = sel ? bv : bk;
    const float* lg = lang + b * 256 * 20 + l;
    float acc = bb[o];
    #pragma unroll 8
    for (int c = 0; c < 256; ++c)
        acc = fmaf(W[o * 256 + c], lg[c * 20], acc);
    (sel ? vout : kout)[b * 2560 + o * 20 + l] = acc;
}

// convert the six 128x128 f32 weights to bf16 row-major
__global__ __launch_bounds__(256) void wprep_kernel(
    const float* __restrict__ w0, const float* __restrict__ w1,
    const float* __restrict__ w2, const float* __restrict__ w3,
    const float* __restrict__ w4, const float* __restrict__ w5,
    short* __restrict__ wt)
{
    const int m = blockIdx.x >> 4, s = blockIdx.x & 15;
    const float* src = w0;
    if (m == 1) src = w1; else if (m == 2) src = w2; else if (m == 3) src = w3;
    else if (m == 4) src = w4; else if (m == 5) src = w5;
    short* dst = wt + m * NCH * NCH;
    const int i0 = s * 1024 + threadIdx.x * 4;
    f32x4 v = *(const f32x4*)(src + i0);
    short s4[4] = {f2bf(v[0]), f2bf(v[1]), f2bf(v[2]), f2bf(v[3])};
    *(uint2*)(dst + i0) = make_uint2(
        pk2s(s4[0], s4[1]), pk2s(s4[2], s4[3]));
}

// after g12: kn[b][c][l] = 0.25*rq_c*k[c][l];  cb[b][h][l] = sum_{c in h} mq_c*kn
__global__ __launch_bounds__(256) void knprep_kernel(
    const float* __restrict__ qs, const float* __restrict__ qs2,
    const float* __restrict__ kbuf,
    float* __restrict__ knb, float* __restrict__ cbb)
{
    __shared__ float mq[128], rqs[128], knl[2560];
    const int t = threadIdx.x, b = blockIdx.x;
    if (t < 128) {
        float m = qs[b * 128 + t] * (1.0f / PSP);
        float v = qs2[b * 128 + t] * (1.0f / PSP) - m * m;
        mq[t] = m;
        rqs[t] = rsqrtf(v + EPSV) * 0.25f;
    }
    __syncthreads();
    for (int e = t; e < 2560; e += 256) {
        int c = e / 20;
        float kv = rqs[c] * kbuf[b * 2560 + e];
        knl[e] = kv;
        knb[b * 2560 + e] = kv;
    }
    __syncthreads();
    if (t < 160) {
        int h = t / 20, l = t % 20;
        float s = 0.0f;
        #pragma unroll
        for (int i = 0; i < 16; ++i)
            s = fmaf(mq[h * 16 + i], knl[(h * 16 + i) * 20 + l], s);
        cbb[b * 160 + t] = s;
    }
}

// ---------------------------------------------------------------------------
// GEMM building blocks
// ---------------------------------------------------------------------------
struct RawF32 { f32x4 a[4], b[4]; };
struct RawB16 { bf16x8 a0, a1, b0, b1; };

static __device__ __forceinline__ void ld_raw_f32(const float* src, RawF32& r) {
    const int t = threadIdx.x;
    const float* s0 = src + (size_t)(2 * (t >> 2)) * PSP + (t & 3) * 16;
    #pragma unroll
    for (int i = 0; i < 4; ++i) {
        r.a[i] = *(const f32x4*)(s0 + i * 4);
        r.b[i] = *(const f32x4*)(s0 + PSP + i * 4);
    }
}
static __device__ __forceinline__ void st_f32(uint32_t* STG, const RawF32& r) {
    const int t = threadIdx.x;
    uint32_t w[16];
    #pragma unroll
    for (int i = 0; i < 4; ++i)
        #pragma unroll
        for (int j = 0; j < 4; ++j) w[i * 4 + j] = pk2f(r.a[i][j], r.b[i][j]);
    uint32_t* base = STG + (t >> 2) * CPW + (t & 3) * 16;
    #pragma unroll
    for (int k = 0; k < 8; ++k) *(uint2*)(base + 2 * k) = make_uint2(w[2 * k], w[2 * k + 1]);
}
static __device__ __forceinline__ void ld_raw_b16(const short* src, RawB16& r) {
    const int t = threadIdx.x;
    const short* s0 = src + (size_t)(2 * (t >> 2)) * PSP + (t & 3) * 16;
    r.a0 = *(const bf16x8*)s0;         r.a1 = *(const bf16x8*)(s0 + 8);
    r.b0 = *(const bf16x8*)(s0 + PSP); r.b1 = *(const bf16x8*)(s0 + PSP + 8);
}
static __device__ __forceinline__ void st_b16(uint32_t* STG, const RawB16& r) {
    const int t = threadIdx.x;
    uint32_t w[16];
    #pragma unroll
    for (int k = 0; k < 8; ++k) { w[k] = pk2s(r.a0[k], r.b0[k]); w[8 + k] = pk2s(r.a1[k], r.b1[k]); }
    uint32_t* base = STG + (t >> 2) * CPW + (t & 3) * 16;
    #pragma unroll
    for (int k = 0; k < 8; ++k) *(uint2*)(base + 2 * k) = make_uint2(w[2 * k], w[2 * k + 1]);
}
// g4 staging: norm(skip)*norm(wgt)
static __device__ __forceinline__ void st_g4(uint32_t* STG, const RawB16& rs, const RawB16& rw,
                                             const float nm[4][NCH]) {
    const int t = threadIdx.x;
    const int c = 2 * (t >> 2);
    const float mA0 = nm[0][c], rA0 = nm[1][c], mA1 = nm[0][c+1], rA1 = nm[1][c+1];
    const float mB0 = nm[2][c], rB0 = nm[3][c], mB1 = nm[2][c+1], rB1 = nm[3][c+1];
    uint32_t w[16];
    #pragma unroll
    for (int k = 0; k < 8; ++k) {
        float lo  = ((bf2f(rs.a0[k]) - mA0) * rA0) * ((bf2f(rw.a0[k]) - mB0) * rB0);
        float hi  = ((bf2f(rs.b0[k]) - mA1) * rA1) * ((bf2f(rw.b0[k]) - mB1) * rB1);
        float lo2 = ((bf2f(rs.a1[k]) - mA0) * rA0) * ((bf2f(rw.a1[k]) - mB0) * rB0);
        float hi2 = ((bf2f(rs.b1[k]) - mA1) * rA1) * ((bf2f(rw.b1[k]) - mB1) * rB1);
        w[k] = pk2f(lo, hi); w[8 + k] = pk2f(lo2, hi2);
    }
    uint32_t* base = STG + (t >> 2) * CPW + (t & 3) * 16;
    #pragma unroll
    for (int k = 0; k < 8; ++k) *(uint2*)(base + 2 * k) = make_uint2(w[2 * k], w[2 * k + 1]);
}

static __device__ __forceinline__ void load_afrag16(const short* __restrict__ W16,
                                                    int wid, int lane, bf16x8 af[2][4]) {
    const int orow = wid * 32 + (lane & 15);
    const int cb   = (lane >> 4) * 8;
    #pragma unroll
    for (int mt = 0; mt < 2; ++mt)
        #pragma unroll
        for (int kt = 0; kt < 4; ++kt)
            af[mt][kt] = *(const bf16x8*)(W16 + (size_t)(orow + mt * 16) * NCH + kt * 32 + cb);
}

static __device__ __forceinline__ bf16x8 read_bfrag(const uint32_t* CP, int c2b, int p) {
    union { uint32_t u[4]; bf16x8 f; } cv;
    #pragma unroll
    for (int i = 0; i < 4; ++i) cv.u[i] = CP[(c2b + i) * CPW + p];
    return cv.f;
}
static __device__ __forceinline__ void run_mfma(const uint32_t* CP, const bf16x8 af[2][4],
                                                f32x4 acc[2][4], int lane) {
    const int l15 = lane & 15, kh = lane >> 4;
    #pragma unroll
    for (int nt = 0; nt < 4; ++nt) {
        const int p = nt * 16 + l15;
        bf16x8 bf[4];
        #pragma unroll
        for (int kt = 0; kt < 4; ++kt) bf[kt] = read_bfrag(CP, kt * 16 + kh * 4, p);
        #pragma unroll
        for (int kt = 0; kt < 4; ++kt) {
            acc[0][nt] = __builtin_amdgcn_mfma_f32_16x16x32_bf16(af[0][kt], bf[kt], acc[0][nt], 0, 0, 0);
            acc[1][nt] = __builtin_amdgcn_mfma_f32_16x16x32_bf16(af[1][kt], bf[kt], acc[1][nt], 0, 0, 0);
        }
    }
}
static __device__ __forceinline__ void zero_acc(f32x4 acc[2][4]) {
    #pragma unroll
    for (int m = 0; m < 2; ++m)
        #pragma unroll
        for (int n = 0; n < 4; ++n) acc[m][n] = (f32x4)0.0f;
}
// pack acc (4 consecutive o at fixed p) into bf16-pair LCp [o2][CPW]
static __device__ __forceinline__ void write_LCp(uint32_t* LCp, const f32x4 acc[2][4],
                                                 int wid, int lane) {
    const int l15 = lane & 15, og = wid * 32 + (lane >> 4) * 4;
    #pragma unroll
    for (int mt = 0; mt < 2; ++mt)
        #pragma unroll
        for (int nt = 0; nt < 4; ++nt) {
            const int o2 = (og >> 1) + mt * 8, p = nt * 16 + l15;
            f32x4 a = acc[mt][nt];
            LCp[o2 * CPW + p]       = pk2f(a[0], a[1]);
            LCp[(o2 + 1) * CPW + p] = pk2f(a[2], a[3]);
        }
}
// epilogue: unpack LCp, +bias (+relu), coalesced bf16 store, optional stats->sred
template<bool RELU, bool STATS>
static __device__ __forceinline__ void epi_store(const uint32_t* LCp, const float* __restrict__ bias,
        short* __restrict__ dst, float* sredS, float* sredQ)
{
    const int t = threadIdx.x;
    #pragma unroll
    for (int r = 0; r < 4; ++r) {
        const int u = r * 256 + t, o = u >> 3, ch = u & 7, hi = o & 1;
        const float bia = bias[o];
        const uint32_t* src = LCp + (o >> 1) * CPW + ch * 8;
        float v[8];
        #pragma unroll
        for (int j = 0; j < 4; ++j) {
            uint2 ww = *(const uint2*)(src + 2 * j);
            v[2*j]   = (hi ? bfHI(ww.x) : bfLO(ww.x)) + bia;
            v[2*j+1] = (hi ? bfHI(ww.y) : bfLO(ww.y)) + bia;
        }
        if (RELU) {
            #pragma unroll
            for (int j = 0; j < 8; ++j) v[j] = fmaxf(v[j], 0.0f);
        }
        bf16x8 s8;
        #pragma unroll
        for (int j = 0; j < 8; ++j) s8[j] = f2bf(v[j]);
        *(bf16x8*)(dst + (size_t)o * PSP + ch * 8) = s8;
        if (STATS) {
            float s = 0.0f, q = 0.0f;
            #pragma unroll
            for (int j = 0; j < 8; ++j) { s += v[j]; q += v[j] * v[j]; }
            s += __shfl_xor(s, 1); q += __shfl_xor(q, 1);
            s += __shfl_xor(s, 2); q += __shfl_xor(q, 2);
            s += __shfl_xor(s, 4); q += __shfl_xor(q, 4);
            if ((t & 7) == 0) { sredS[o] = s; sredQ[o] = q; }
        }
    }
}

// ---------------------------------------------------------------------------
// G12: q_pre = Wq*img (+stats) and skip_pre = Wpi*img (+stats); img read once.
// Multi-tile, double-buffered staging.
// ---------------------------------------------------------------------------
__global__ __launch_bounds__(256) void g12_kernel(
    const float* __restrict__ img, const short* __restrict__ w16,
    const float* __restrict__ bq, const float* __restrict__ bpi,
    short* __restrict__ qout, short* __restrict__ sout,
    float* __restrict__ qs, float* __restrict__ qs2,
    float* __restrict__ ss, float* __restrict__ ss2)
{
    __shared__ __align__(16) uint32_t STG[2][64 * CPW];
    __shared__ __align__(16) uint32_t LCp[64 * CPW];
    __shared__ float sredS[128], sredQ[128];

    const int t = threadIdx.x, lane = t & 63, wid = t >> 6;
    const int b = blockIdx.y;
    const size_t bbase = (size_t)b * NCH * PSP;
    const int pbase = blockIdx.x * (64 * TPB);
    const int sb = b * NCH;                       // per-batch stats offset

    bf16x8 afq[2][4], afp[2][4];
    load_afrag16(w16, wid, lane, afq);
    load_afrag16(w16 + NCH * NCH, wid, lane, afp);

    RawF32 rw;
    ld_raw_f32(img + bbase + pbase, rw);
    st_f32(STG[0], rw);
    __syncthreads();

    for (int i = 0; i < TPB; ++i) {
        const int cur = i & 1, nxt = cur ^ 1;
        const int pblk = pbase + i * 64;
        if (i + 1 < TPB) ld_raw_f32(img + bbase + pblk + 64, rw);
        f32x4 acc[2][4];
        zero_acc(acc);
        run_mfma(STG[cur], afq, acc, lane);
        __syncthreads();                                    // a
        if (i + 1 < TPB) st_f32(STG[nxt], rw);
        write_LCp(LCp, acc, wid, lane);
        __syncthreads();                                    // b
        zero_acc(acc);
        run_mfma(STG[cur], afp, acc, lane);
        epi_store<false, true>(LCp, bq, qout + bbase + pblk, sredS, sredQ);
        __syncthreads();                                    // c
        if (t < 128) { atomicAdd(&qs[sb + t], sredS[t]); atomicAdd(&qs2[sb + t], sredQ[t]); }
        write_LCp(LCp, acc, wid, lane);
        __syncthreads();                                    // d
        epi_store<false, true>(LCp, bpi, sout + bbase + pblk, sredS, sredQ);
        __syncthreads();                                    // e
        if (t < 128) { atomicAdd(&ss[sb + t], sredS[t]); atomicAdd(&ss2[sb + t], sredQ[t]); }
    }
}

// ---------------------------------------------------------------------------
// G3: weight_pre = Wpw * x (+stats)
// ---------------------------------------------------------------------------
__global__ __launch_bounds__(256) void g3_kernel(
    const short* __restrict__ x, const short* __restrict__ w16,
    const float* __restrict__ bpw, short* __restrict__ wout,
    float* __restrict__ wsu, float* __restrict__ ws2)
{
    __shared__ __align__(16) uint32_t STG[2][64 * CPW];
    __shared__ __align__(16) uint32_t LCp[64 * CPW];
    __shared__ float sredS[128], sredQ[128];

    const int t = threadIdx.x, lane = t & 63, wid = t >> 6;
    const int b = blockIdx.y;
    const size_t bbase = (size_t)b * NCH * PSP;
    const int pbase = blockIdx.x * (64 * TPB);
    const int sb = b * NCH;                       // per-batch stats offset

    bf16x8 af[2][4];
    load_afrag16(w16, wid, lane, af);

    RawB16 rw;
    ld_raw_b16(x + bbase + pbase, rw);
    st_b16(STG[0], rw);
    __syncthreads();

    for (int i = 0; i < TPB; ++i) {
        const int cur = i & 1, nxt = cur ^ 1;
        const int pblk = pbase + i * 64;
        if (i + 1 < TPB) ld_raw_b16(x + bbase + pblk + 64, rw);
        f32x4 acc[2][4];
        zero_acc(acc);
        run_mfma(STG[cur], af, acc, lane);
        __syncthreads();                                    // a
        if (i + 1 < TPB) st_b16(STG[nxt], rw);
        write_LCp(LCp, acc, wid, lane);
        __syncthreads();                                    // b
        epi_store<false, true>(LCp, bpw, wout + bbase + pblk, sredS, sredQ);
        __syncthreads();                                    // c
        if (t < 128) { atomicAdd(&wsu[sb + t], sredS[t]); atomicAdd(&ws2[sb + t], sredQ[t]); }
    }
}

// ---------------------------------------------------------------------------
// G4: out = relu(Wpo * (norm(skip)*norm(weight)))
// ---------------------------------------------------------------------------
__global__ __launch_bounds__(256) void g4_kernel(
    const short* __restrict__ skip, const short* __restrict__ wgt,
    const float* __restrict__ sA, const float* __restrict__ sA2,
    const float* __restrict__ sB, const float* __restrict__ sB2,
    const short* __restrict__ w16, const float* __restrict__ bpo,
    short* __restrict__ outp)
{
    __shared__ __align__(16) uint32_t STG[2][64 * CPW];
    __shared__ __align__(16) uint32_t LCp[64 * CPW];
    __shared__ float nm[4][NCH];

    const int t = threadIdx.x, lane = t & 63, wid = t >> 6;
    const int b = blockIdx.y;
    const size_t bbase = (size_t)b * NCH * PSP;
    const int pbase = blockIdx.x * (64 * TPB);

    if (t < NCH) {
        float m = sA[b * NCH + t] * (1.0f / PSP);
        float v = sA2[b * NCH + t] * (1.0f / PSP) - m * m;
        nm[0][t] = m; nm[1][t] = rsqrtf(v + EPSV);
    } else {
        int c = t - NCH;
        float m = sB[b * NCH + c] * (1.0f / PSP);
        float v = sB2[b * NCH + c] * (1.0f / PSP) - m * m;
        nm[2][c] = m; nm[3][c] = rsqrtf(v + EPSV);
    }

    bf16x8 af[2][4];
    load_afrag16(w16, wid, lane, af);

    RawB16 rs, rw;
    ld_raw_b16(skip + bbase + pbase, rs);
    ld_raw_b16(wgt  + bbase + pbase, rw);
    __syncthreads();                 // nm ready
    st_g4(STG[0], rs, rw, nm);
    __syncthreads();

    for (int i = 0; i < TPB; ++i) {
        const int cur = i & 1, nxt = cur ^ 1;
        const int pblk = pbase + i * 64;
        if (i + 1 < TPB) {
            ld_raw_b16(skip + bbase + pblk + 64, rs);
            ld_raw_b16(wgt  + bbase + pblk + 64, rw);
        }
        f32x4 acc[2][4];
        zero_acc(acc);
        run_mfma(STG[cur], af, acc, lane);
        __syncthreads();                                    // a
        if (i + 1 < TPB) st_g4(STG[nxt], rs, rw, nm);
        write_LCp(LCp, acc, wid, lane);
        __syncthreads();                                    // b
        epi_store<true, false>(LCp, bpo, outp + bbase + pblk, nullptr, nullptr);
    }
}

// ---------------------------------------------------------------------------
// G56: final = out * tanh(Wg2 * relu(Wg1*out + bg1) + bg2)
// ---------------------------------------------------------------------------
__global__ __launch_bounds__(256) void g56_kernel(
    const short* __restrict__ outb, const short* __restrict__ w16g1,
    const float* __restrict__ bg1, const short* __restrict__ w16g2,
    const float* __restrict__ bg2, float* __restrict__ fin)
{
    __shared__ __align__(16) uint32_t STG[2][64 * CPW];
    __shared__ __align__(16) uint32_t RT[64 * CPW];
    __shared__ __align__(16) uint32_t LCp[64 * CPW];

    const int t = threadIdx.x, lane = t & 63, wid = t >> 6;
    const int b = blockIdx.y;
    const size_t bbase = (size_t)b * NCH * PSP;
    const int pbase = blockIdx.x * (64 * TPB);

    bf16x8 af1[2][4], af2[2][4];
    load_afrag16(w16g1, wid, lane, af1);
    load_afrag16(w16g2, wid, lane, af2);

    float bg1v[2][4];
    {
        const int og = wid * 32 + (lane >> 4) * 4;
        #pragma unroll
        for (int mt = 0; mt < 2; ++mt)
            #pragma unroll
            for (int r = 0; r < 4; ++r) bg1v[mt][r] = bg1[og + mt * 16 + r];
    }

    RawB16 rw;
    ld_raw_b16(outb + bbase + pbase, rw);
    st_b16(STG[0], rw);
    __syncthreads();

    for (int i = 0; i < TPB; ++i) {
        const int cur = i & 1, nxt = cur ^ 1;
        const int pblk = pbase + i * 64;
        if (i + 1 < TPB) ld_raw_b16(outb + bbase + pblk + 64, rw);
        f32x4 acc[2][4];
        zero_acc(acc);
        run_mfma(STG[cur], af1, acc, lane);
        __syncthreads();                                    // a
        // relu1 -> RT
        {
            const int l15 = lane & 15, og = wid * 32 + (lane >> 4) * 4;
            #pragma unroll
            for (int mt = 0; mt < 2; ++mt)
                #pragma unroll
                for (int nt = 0; nt < 4; ++nt) {
                    const int o2 = (og >> 1) + mt * 8, p = nt * 16 + l15;
                    f32x4 a = acc[mt][nt];
                    float z0 = fmaxf(a[0] + bg1v[mt][0], 0.0f);
                    float z1 = fmaxf(a[1] + bg1v[mt][1], 0.0f);
                    float z2 = fmaxf(a[2] + bg1v[mt][2], 0.0f);
                    float z3 = fmaxf(a[3] + bg1v[mt][3], 0.0f);
                    RT[o2 * CPW + p]       = pk2f(z0, z1);
                    RT[(o2 + 1) * CPW + p] = pk2f(z2, z3);
                }
        }
        if (i + 1 < TPB) st_b16(STG[nxt], rw);
        __syncthreads();                                    // b
        zero_acc(acc);
        run_mfma(RT, af2, acc, lane);
        write_LCp(LCp, acc, wid, lane);
        __syncthreads();                                    // c
        // final epilogue: f32 = out * tanh(LCp + bg2)
        {
            float* dst = fin + bbase + pblk;
            #pragma unroll
            for (int r = 0; r < 8; ++r) {
                const int u = r * 256 + t, o = u >> 4, ch = u & 15, hi = o & 1;
                const float bia = bg2[o];
                const uint32_t* lc = LCp + (o >> 1) * CPW + ch * 4;
                const uint32_t* mg = STG[cur] + (o >> 1) * CPW + ch * 4;
                uint2 l0 = *(const uint2*)lc, l1 = *(const uint2*)(lc + 2);
                uint2 m0 = *(const uint2*)mg, m1 = *(const uint2*)(mg + 2);
                f32x4 ov;
                ov[0] = (hi ? bfHI(m0.x) : bfLO(m0.x)) * tanhf((hi ? bfHI(l0.x) : bfLO(l0.x)) + bia);
                ov[1] = (hi ? bfHI(m0.y) : bfLO(m0.y)) * tanhf((hi ? bfHI(l0.y) : bfLO(l0.y)) + bia);
                ov[2] = (hi ? bfHI(m1.x) : bfLO(m1.x)) * tanhf((hi ? bfHI(l1.x) : bfLO(l1.x)) + bia);
                ov[3] = (hi ? bfHI(m1.y) : bfLO(m1.y)) * tanhf((hi ? bfHI(l1.y) : bfLO(l1.y)) + bia);
                *(f32x4*)(dst + (size_t)o * PSP + ch * 4) = ov;
            }
        }
    }
}

// ---------------------------------------------------------------------------
// Attention v2: 128 positions/block, 256 threads (2 threads/position, 4 heads each).
// q staged via LDS (coalesced), kn/cb/v via wave-uniform scalar loads,
// x staged back through LDS and written wave-contiguous.
// ---------------------------------------------------------------------------
__global__ __launch_bounds__(256) void attn2_kernel(
    const short* __restrict__ qpre, const float* __restrict__ knb,
    const float* __restrict__ cbb, const float* __restrict__ vbuf,
    short* __restrict__ xout)
{
    __shared__ __align__(16) uint32_t SM[64 * 130];   // QL [64][130]; reused as XB [128][65]
    const int t = threadIdx.x;
    const int b = blockIdx.y;
    const int pblk = blockIdx.x * 128;
    const size_t bbase = (size_t)b * NCH * PSP;

    // stage q tile (128c x 128p) -> QL CP pairs
    {
        const int c2 = t >> 2, p0 = (t & 3) * 16;
        const short* s0 = qpre + bbase + (size_t)(2 * c2) * PSP + pblk + p0;
        #pragma unroll
        for (int half = 0; half < 2; ++half) {
            const short* s = s0 + half * 64;
            bf16x8 a0 = *(const bf16x8*)s,         a1 = *(const bf16x8*)(s + 8);
            bf16x8 b0 = *(const bf16x8*)(s + PSP), b1 = *(const bf16x8*)(s + PSP + 8);
            uint32_t w[16];
            #pragma unroll
            for (int k = 0; k < 8; ++k) { w[k] = pk2s(a0[k], b0[k]); w[8 + k] = pk2s(a1[k], b1[k]); }
            uint32_t* base = SM + c2 * 130 + half * 64 + p0;
            #pragma unroll
            for (int k = 0; k < 8; ++k) *(uint2*)(base + 2 * k) = make_uint2(w[2 * k], w[2 * k + 1]);
        }
    }
    __syncthreads();

    const int p = t & 127, hg = t >> 7;    // hg: head-group 0 (h0-3) / 1 (h4-7)
    uint32_t qw[32];
    #pragma unroll
    for (int i = 0; i < 32; ++i) qw[i] = SM[(hg * 32 + i) * 130 + p];
    __syncthreads();                        // QL free -> XB

    const float* kn = knb + b * 2560;
    const float* cb = cbb + b * 160;
    const float* vv = vbuf + b * 2560;

    #pragma unroll 1
    for (int hp = 0; hp < 4; ++hp) {
        const int h = hg * 4 + hp;
        const int c0 = h * 16;
        float sim[20];
        #pragma unroll
        for (int l = 0; l < 20; ++l) sim[l] = -cb[h * 20 + l];
        #pragma unroll
        for (int i = 0; i < 8; ++i) {
            const uint32_t w = qw[hp * 8 + i];
            const float qlo = bfLO(w), qhi = bfHI(w);
            const float* k0 = kn + (c0 + 2 * i) * 20;
            #pragma unroll
            for (int l4 = 0; l4 < 5; ++l4) {
                f32x4 ka = *(const f32x4*)(k0 + 4 * l4);
                f32x4 kb = *(const f32x4*)(k0 + 20 + 4 * l4);
                #pragma unroll
                for (int j = 0; j < 4; ++j)
                    sim[4 * l4 + j] = fmaf(qlo, ka[j], fmaf(qhi, kb[j], sim[4 * l4 + j]));
            }
        }
        float mx = sim[0];
        #pragma unroll
        for (int l = 1; l < 20; ++l) mx = fmaxf(mx, sim[l]);
        float se = 0.0f;
        #pragma unroll
        for (int l = 0; l < 20; ++l) { float e = __expf(sim[l] - mx); sim[l] = e; se += e; }
        const float inv = 1.0f / se;
        #pragma unroll
        for (int i = 0; i < 8; ++i) {
            const float* v0 = vv + (c0 + 2 * i) * 20;
            float x0 = 0.0f, x1 = 0.0f;
            #pragma unroll
            for (int l4 = 0; l4 < 5; ++l4) {
                f32x4 va = *(const f32x4*)(v0 + 4 * l4);
                f32x4 vb = *(const f32x4*)(v0 + 20 + 4 * l4);
                #pragma unroll
                for (int j = 0; j < 4; ++j) {
                    x0 = fmaf(sim[4 * l4 + j], va[j], x0);
                    x1 = fmaf(sim[4 * l4 + j], vb[j], x1);
                }
            }
            SM[p * 65 + hg * 32 + hp * 8 + i] = pk2f(x0 * inv, x1 * inv);
        }
    }
    __syncthreads();

    // coalesced copyout: 128 pos x 256B, wave-contiguous 1KB per store step
    {
        const int lane = t & 63, w = t >> 6;
        uint32_t* gdst = (uint32_t*)(xout + bbase + (size_t)pblk * NCH);
        #pragma unroll
        for (int j = 0; j < 8; ++j) {
            const int pp = w * 32 + j * 4 + (lane >> 4);
            const int cw = (lane & 15) * 4;
            const uint32_t* s = SM + pp * 65 + cw;
            uint32_t u0 = s[0], u1 = s[1], u2 = s[2], u3 = s[3];
            *(uint4*)(gdst + pp * 64 + cw) = make_uint4(u0, u1, u2, u3);
        }
    }
}

// ---------------------------------------------------------------------------
extern "C" void kernel_launch(void* const* d_in, const int* in_sizes, int n_in,
                              void* d_out, int out_size, void* d_ws, size_t ws_size,
                              hipStream_t stream)
{
    const float* img  = (const float*)d_in[0];
    const float* lang = (const float*)d_in[1];
    const float* Wq   = (const float*)d_in[2];
    const float* bq   = (const float*)d_in[3];
    const float* Wk   = (const float*)d_in[4];
    const float* bk   = (const float*)d_in[5];
    const float* Wv   = (const float*)d_in[6];
    const float* bv   = (const float*)d_in[7];
    const float* Wpw  = (const float*)d_in[8];
    const float* bpw  = (const float*)d_in[9];
    const float* Wpi  = (const float*)d_in[10];
    const float* bpi  = (const float*)d_in[11];
    const float* Wpo  = (const float*)d_in[12];
    const float* bpo  = (const float*)d_in[13];
    const float* Wg1  = (const float*)d_in[14];
    const float* bg1  = (const float*)d_in[15];
    const float* Wg2  = (const float*)d_in[16];
    const float* bg2  = (const float*)d_in[17];
    float* outp = (float*)d_out;

    const size_t N = (size_t)NB * NCH * PSP;
    const size_t needed = 3 * N * sizeof(short) + 6 * NCH * NCH * sizeof(short)
                        + (3 * 2 * 2560 + 2 * 160 + 6 * 256) * sizeof(float);
    if (ws_size < needed) return;

    short* bufA = (short*)d_ws;          // q_pre, then weight_pre
    short* bufB = bufA + N;              // x, then 'out'
    short* bufC = bufB + N;              // skip_pre
    short* wt16 = bufC + N;              // 6 x 128x128 bf16 weights
    float* kbuf = (float*)(wt16 + 6 * NCH * NCH);
    float* vbuf = kbuf + 2 * 2560;
    float* knb  = vbuf + 2 * 2560;
    float* cbb  = knb + 2 * 2560;
    float* st   = cbb + 2 * 160;
    float* qs   = st;
    float* qs2  = st + 256;
    float* ss   = st + 512;
    float* ss2  = st + 768;
    float* wsu  = st + 1024;
    float* ws2  = st + 1280;

    hipMemsetAsync(st, 0, 6 * 256 * sizeof(float), stream);
    kv_kernel<<<dim3(40), dim3(256), 0, stream>>>(lang, Wk, bk, Wv, bv, kbuf, vbuf);
    // order in wt16: Wq, Wpi, Wpw, Wpo, Wg1, Wg2
    wprep_kernel<<<dim3(96), dim3(256), 0, stream>>>(Wq, Wpi, Wpw, Wpo, Wg1, Wg2, wt16);

    const dim3 gg(PSP / (64 * TPB), NB), gb(256);

    // q_pre -> bufA, skip_pre -> bufC (img read once)
    g12_kernel<<<gg, gb, 0, stream>>>(img, wt16, bq, bpi, bufA, bufC, qs, qs2, ss, ss2);
    // kn / cb from q stats + k
    knprep_kernel<<<dim3(NB), dim3(256), 0, stream>>>(qs, qs2, kbuf, knb, cbb);
    // attention: q_pre -> x (bufB), flat (b,p,c) order == x_img c-major
    attn2_kernel<<<dim3(PSP / 128, NB), gb, 0, stream>>>(bufA, knb, cbb, vbuf, bufB);
    // weight_pre = Wpw * x (+stats) -> bufA
    g3_kernel<<<gg, gb, 0, stream>>>(bufB, wt16 + 2 * NCH * NCH, bpw, bufA, wsu, ws2);
    // out = relu(Wpo*(norm(skip)*norm(weight))) -> bufB
    g4_kernel<<<gg, gb, 0, stream>>>(bufC, bufA, ss, ss2, wsu, ws2,
                                     wt16 + 3 * NCH * NCH, bpo, bufB);
    // final -> d_out
    g56_kernel<<<gg, gb, 0, stream>>>(bufB, wt16 + 4 * NCH * NCH, bg1,
                                      wt16 + 5 * NCH * NCH, bg2, outp);
}

// Round 7
// 359.040 us; speedup vs baseline: 3.6063x; 1.1676x over previous
//
#include <hip/hip_runtime.h>
#include <cstdint>
#include <cstddef>

#define PSP 110592          // 48*48*48 positions per batch
#define NCH 128
#define NB  2
#define CPW 66              // u32 stride of CP-layout rows (64 + 2 pad)
#define TPB 4               // 64-pos tiles per GEMM block
static constexpr float EPSV = 1e-5f;

typedef short bf16x8 __attribute__((ext_vector_type(8)));
typedef float f32x4  __attribute__((ext_vector_type(4)));

static __device__ __forceinline__ short f2bf(float f) {
    uint32_t u = __builtin_bit_cast(uint32_t, f);
    u += 0x7FFF + ((u >> 16) & 1);          // RNE
    return (short)(u >> 16);
}
static __device__ __forceinline__ float bf2f(short s) {
    uint32_t u = ((uint32_t)(uint16_t)s) << 16;
    return __builtin_bit_cast(float, u);
}
static __device__ __forceinline__ float bfLO(uint32_t w) { return bf2f((short)(w & 0xffff)); }
static __device__ __forceinline__ float bfHI(uint32_t w) { return bf2f((short)(w >> 16)); }
static __device__ __forceinline__ uint32_t pk2f(float lo, float hi) {
    return (uint32_t)(uint16_t)f2bf(lo) | ((uint32_t)(uint16_t)f2bf(hi) << 16);
}
static __device__ __forceinline__ uint32_t pk2s(short lo, short hi) {
    return (uint32_t)(uint16_t)lo | ((uint32_t)(uint16_t)hi << 16);
}

// ---------------------------------------------------------------------------
// tiny kernels
// ---------------------------------------------------------------------------
__global__ __launch_bounds__(256) void kv_kernel(
    const float* __restrict__ lang,
    const float* __restrict__ Wk, const float* __restrict__ bk,
    const float* __restrict__ Wv, const float* __restrict__ bv,
    float* __restrict__ kout, float* __restrict__ vout)
{
    int gid = blockIdx.x * 256 + threadIdx.x;     // 0..10239
    int sel = gid / 5120;
    int r   = gid % 5120;
    int b   = r / 2560;
    int o   = (r % 2560) / 20;
    int l   = r % 20;
    const float* W  = sel ? Wv : Wk;
    const float* bb = sel ? bv : bk;
    const float* lg = lang + b * 256 * 20 + l;
    float acc = bb[o];
    #pragma unroll 8
    for (int c = 0; c < 256; ++c)
        acc = fmaf(W[o * 256 + c], lg[c * 20], acc);
    (sel ? vout : kout)[b * 2560 + o * 20 + l] = acc;
}

// convert the six 128x128 f32 weights to bf16 row-major
__global__ __launch_bounds__(256) void wprep_kernel(
    const float* __restrict__ w0, const float* __restrict__ w1,
    const float* __restrict__ w2, const float* __restrict__ w3,
    const float* __restrict__ w4, const float* __restrict__ w5,
    short* __restrict__ wt)
{
    const int m = blockIdx.x >> 4, s = blockIdx.x & 15;
    const float* src = w0;
    if (m == 1) src = w1; else if (m == 2) src = w2; else if (m == 3) src = w3;
    else if (m == 4) src = w4; else if (m == 5) src = w5;
    short* dst = wt + m * NCH * NCH;
    const int i0 = s * 1024 + threadIdx.x * 4;
    f32x4 v = *(const f32x4*)(src + i0);
    short s4[4] = {f2bf(v[0]), f2bf(v[1]), f2bf(v[2]), f2bf(v[3])};
    *(uint2*)(dst + i0) = make_uint2(
        pk2s(s4[0], s4[1]), pk2s(s4[2], s4[3]));
}

// after g12: kn[b][c][l] = 0.25*rq_c*k[c][l];  cb[b][h][l] = sum_{c in h} mq_c*kn
__global__ __launch_bounds__(256) void knprep_kernel(
    const float* __restrict__ qs, const float* __restrict__ qs2,
    const float* __restrict__ kbuf,
    float* __restrict__ knb, float* __restrict__ cbb)
{
    __shared__ float mq[128], rqs[128], knl[2560];
    const int t = threadIdx.x, b = blockIdx.x;
    if (t < 128) {
        float m = qs[b * 128 + t] * (1.0f / PSP);
        float v = qs2[b * 128 + t] * (1.0f / PSP) - m * m;
        mq[t] = m;
        rqs[t] = rsqrtf(v + EPSV) * 0.25f;
    }
    __syncthreads();
    for (int e = t; e < 2560; e += 256) {
        int c = e / 20;
        float kv = rqs[c] * kbuf[b * 2560 + e];
        knl[e] = kv;
        knb[b * 2560 + e] = kv;
    }
    __syncthreads();
    if (t < 160) {
        int h = t / 20, l = t % 20;
        float s = 0.0f;
        #pragma unroll
        for (int i = 0; i < 16; ++i)
            s = fmaf(mq[h * 16 + i], knl[(h * 16 + i) * 20 + l], s);
        cbb[b * 160 + t] = s;
    }
}

// ---------------------------------------------------------------------------
// GEMM building blocks
// ---------------------------------------------------------------------------
struct RawF32 { f32x4 a[4], b[4]; };
struct RawB16 { bf16x8 a0, a1, b0, b1; };

static __device__ __forceinline__ void ld_raw_f32(const float* src, RawF32& r) {
    const int t = threadIdx.x;
    const float* s0 = src + (size_t)(2 * (t >> 2)) * PSP + (t & 3) * 16;
    #pragma unroll
    for (int i = 0; i < 4; ++i) {
        r.a[i] = *(const f32x4*)(s0 + i * 4);
        r.b[i] = *(const f32x4*)(s0 + PSP + i * 4);
    }
}
static __device__ __forceinline__ void st_f32(uint32_t* STG, const RawF32& r) {
    const int t = threadIdx.x;
    uint32_t w[16];
    #pragma unroll
    for (int i = 0; i < 4; ++i)
        #pragma unroll
        for (int j = 0; j < 4; ++j) w[i * 4 + j] = pk2f(r.a[i][j], r.b[i][j]);
    uint32_t* base = STG + (t >> 2) * CPW + (t & 3) * 16;
    #pragma unroll
    for (int k = 0; k < 8; ++k) *(uint2*)(base + 2 * k) = make_uint2(w[2 * k], w[2 * k + 1]);
}
static __device__ __forceinline__ void ld_raw_b16(const short* src, RawB16& r) {
    const int t = threadIdx.x;
    const short* s0 = src + (size_t)(2 * (t >> 2)) * PSP + (t & 3) * 16;
    r.a0 = *(const bf16x8*)s0;         r.a1 = *(const bf16x8*)(s0 + 8);
    r.b0 = *(const bf16x8*)(s0 + PSP); r.b1 = *(const bf16x8*)(s0 + PSP + 8);
}
static __device__ __forceinline__ void st_b16(uint32_t* STG, const RawB16& r) {
    const int t = threadIdx.x;
    uint32_t w[16];
    #pragma unroll
    for (int k = 0; k < 8; ++k) { w[k] = pk2s(r.a0[k], r.b0[k]); w[8 + k] = pk2s(r.a1[k], r.b1[k]); }
    uint32_t* base = STG + (t >> 2) * CPW + (t & 3) * 16;
    #pragma unroll
    for (int k = 0; k < 8; ++k) *(uint2*)(base + 2 * k) = make_uint2(w[2 * k], w[2 * k + 1]);
}
// g4 staging: norm(skip)*norm(wgt)
static __device__ __forceinline__ void st_g4(uint32_t* STG, const RawB16& rs, const RawB16& rw,
                                             const float nm[4][NCH]) {
    const int t = threadIdx.x;
    const int c = 2 * (t >> 2);
    const float mA0 = nm[0][c], rA0 = nm[1][c], mA1 = nm[0][c+1], rA1 = nm[1][c+1];
    const float mB0 = nm[2][c], rB0 = nm[3][c], mB1 = nm[2][c+1], rB1 = nm[3][c+1];
    uint32_t w[16];
    #pragma unroll
    for (int k = 0; k < 8; ++k) {
        float lo  = ((bf2f(rs.a0[k]) - mA0) * rA0) * ((bf2f(rw.a0[k]) - mB0) * rB0);
        float hi  = ((bf2f(rs.b0[k]) - mA1) * rA1) * ((bf2f(rw.b0[k]) - mB1) * rB1);
        float lo2 = ((bf2f(rs.a1[k]) - mA0) * rA0) * ((bf2f(rw.a1[k]) - mB0) * rB0);
        float hi2 = ((bf2f(rs.b1[k]) - mA1) * rA1) * ((bf2f(rw.b1[k]) - mB1) * rB1);
        w[k] = pk2f(lo, hi); w[8 + k] = pk2f(lo2, hi2);
    }
    uint32_t* base = STG + (t >> 2) * CPW + (t & 3) * 16;
    #pragma unroll
    for (int k = 0; k < 8; ++k) *(uint2*)(base + 2 * k) = make_uint2(w[2 * k], w[2 * k + 1]);
}

static __device__ __forceinline__ void load_afrag16(const short* __restrict__ W16,
                                                    int wid, int lane, bf16x8 af[2][4]) {
    const int orow = wid * 32 + (lane & 15);
    const int cb   = (lane >> 4) * 8;
    #pragma unroll
    for (int mt = 0; mt < 2; ++mt)
        #pragma unroll
        for (int kt = 0; kt < 4; ++kt)
            af[mt][kt] = *(const bf16x8*)(W16 + (size_t)(orow + mt * 16) * NCH + kt * 32 + cb);
}

static __device__ __forceinline__ bf16x8 read_bfrag(const uint32_t* CP, int c2b, int p) {
    union { uint32_t u[4]; bf16x8 f; } cv;
    #pragma unroll
    for (int i = 0; i < 4; ++i) cv.u[i] = CP[(c2b + i) * CPW + p];
    return cv.f;
}
static __device__ __forceinline__ void run_mfma(const uint32_t* CP, const bf16x8 af[2][4],
                                                f32x4 acc[2][4], int lane) {
    const int l15 = lane & 15, kh = lane >> 4;
    #pragma unroll
    for (int nt = 0; nt < 4; ++nt) {
        const int p = nt * 16 + l15;
        bf16x8 bf[4];
        #pragma unroll
        for (int kt = 0; kt < 4; ++kt) bf[kt] = read_bfrag(CP, kt * 16 + kh * 4, p);
        #pragma unroll
        for (int kt = 0; kt < 4; ++kt) {
            acc[0][nt] = __builtin_amdgcn_mfma_f32_16x16x32_bf16(af[0][kt], bf[kt], acc[0][nt], 0, 0, 0);
            acc[1][nt] = __builtin_amdgcn_mfma_f32_16x16x32_bf16(af[1][kt], bf[kt], acc[1][nt], 0, 0, 0);
        }
    }
}
static __device__ __forceinline__ void zero_acc(f32x4 acc[2][4]) {
    #pragma unroll
    for (int m = 0; m < 2; ++m)
        #pragma unroll
        for (int n = 0; n < 4; ++n) acc[m][n] = (f32x4)0.0f;
}
// pack acc (4 consecutive o at fixed p) into bf16-pair LCp [o2][CPW]
static __device__ __forceinline__ void write_LCp(uint32_t* LCp, const f32x4 acc[2][4],
                                                 int wid, int lane) {
    const int l15 = lane & 15, og = wid * 32 + (lane >> 4) * 4;
    #pragma unroll
    for (int mt = 0; mt < 2; ++mt)
        #pragma unroll
        for (int nt = 0; nt < 4; ++nt) {
            const int o2 = (og >> 1) + mt * 8, p = nt * 16 + l15;
            f32x4 a = acc[mt][nt];
            LCp[o2 * CPW + p]       = pk2f(a[0], a[1]);
            LCp[(o2 + 1) * CPW + p] = pk2f(a[2], a[3]);
        }
}
// epilogue: unpack LCp, +bias (+relu), coalesced bf16 store, optional stats->sred
template<bool RELU, bool STATS>
static __device__ __forceinline__ void epi_store(const uint32_t* LCp, const float* __restrict__ bias,
        short* __restrict__ dst, float* sredS, float* sredQ)
{
    const int t = threadIdx.x;
    #pragma unroll
    for (int r = 0; r < 4; ++r) {
        const int u = r * 256 + t, o = u >> 3, ch = u & 7, hi = o & 1;
        const float bia = bias[o];
        const uint32_t* src = LCp + (o >> 1) * CPW + ch * 8;
        float v[8];
        #pragma unroll
        for (int j = 0; j < 4; ++j) {
            uint2 ww = *(const uint2*)(src + 2 * j);
            v[2*j]   = (hi ? bfHI(ww.x) : bfLO(ww.x)) + bia;
            v[2*j+1] = (hi ? bfHI(ww.y) : bfLO(ww.y)) + bia;
        }
        if (RELU) {
            #pragma unroll
            for (int j = 0; j < 8; ++j) v[j] = fmaxf(v[j], 0.0f);
        }
        bf16x8 s8;
        #pragma unroll
        for (int j = 0; j < 8; ++j) s8[j] = f2bf(v[j]);
        *(bf16x8*)(dst + (size_t)o * PSP + ch * 8) = s8;
        if (STATS) {
            float s = 0.0f, q = 0.0f;
            #pragma unroll
            for (int j = 0; j < 8; ++j) { s += v[j]; q += v[j] * v[j]; }
            s += __shfl_xor(s, 1); q += __shfl_xor(q, 1);
            s += __shfl_xor(s, 2); q += __shfl_xor(q, 2);
            s += __shfl_xor(s, 4); q += __shfl_xor(q, 4);
            if ((t & 7) == 0) { sredS[o] = s; sredQ[o] = q; }
        }
    }
}

// ---------------------------------------------------------------------------
// G12: q_pre = Wq*img (+stats) and skip_pre = Wpi*img (+stats); img read once.
// ---------------------------------------------------------------------------
__global__ __launch_bounds__(256) void g12_kernel(
    const float* __restrict__ img, const short* __restrict__ w16,
    const float* __restrict__ bq, const float* __restrict__ bpi,
    short* __restrict__ qout, short* __restrict__ sout,
    float* __restrict__ qs, float* __restrict__ qs2,
    float* __restrict__ ss, float* __restrict__ ss2)
{
    __shared__ __align__(16) uint32_t STG[2][64 * CPW];
    __shared__ __align__(16) uint32_t LCp[64 * CPW];
    __shared__ float sredS[128], sredQ[128];

    const int t = threadIdx.x, lane = t & 63, wid = t >> 6;
    const int b = blockIdx.y;
    const size_t bbase = (size_t)b * NCH * PSP;
    const int pbase = blockIdx.x * (64 * TPB);
    const int sb = b * NCH;                       // per-batch stats offset

    bf16x8 afq[2][4], afp[2][4];
    load_afrag16(w16, wid, lane, afq);
    load_afrag16(w16 + NCH * NCH, wid, lane, afp);

    RawF32 rw;
    ld_raw_f32(img + bbase + pbase, rw);
    st_f32(STG[0], rw);
    __syncthreads();

    for (int i = 0; i < TPB; ++i) {
        const int cur = i & 1, nxt = cur ^ 1;
        const int pblk = pbase + i * 64;
        if (i + 1 < TPB) ld_raw_f32(img + bbase + pblk + 64, rw);
        f32x4 acc[2][4];
        zero_acc(acc);
        run_mfma(STG[cur], afq, acc, lane);
        __syncthreads();                                    // a
        if (i + 1 < TPB) st_f32(STG[nxt], rw);
        write_LCp(LCp, acc, wid, lane);
        __syncthreads();                                    // b
        zero_acc(acc);
        run_mfma(STG[cur], afp, acc, lane);
        epi_store<false, true>(LCp, bq, qout + bbase + pblk, sredS, sredQ);
        __syncthreads();                                    // c
        if (t < 128) { atomicAdd(&qs[sb + t], sredS[t]); atomicAdd(&qs2[sb + t], sredQ[t]); }
        write_LCp(LCp, acc, wid, lane);
        __syncthreads();                                    // d
        epi_store<false, true>(LCp, bpi, sout + bbase + pblk, sredS, sredQ);
        __syncthreads();                                    // e
        if (t < 128) { atomicAdd(&ss[sb + t], sredS[t]); atomicAdd(&ss2[sb + t], sredQ[t]); }
    }
}

// ---------------------------------------------------------------------------
// G3: weight_pre = Wpw * x (+stats)
// ---------------------------------------------------------------------------
__global__ __launch_bounds__(256) void g3_kernel(
    const short* __restrict__ x, const short* __restrict__ w16,
    const float* __restrict__ bpw, short* __restrict__ wout,
    float* __restrict__ wsu, float* __restrict__ ws2)
{
    __shared__ __align__(16) uint32_t STG[2][64 * CPW];
    __shared__ __align__(16) uint32_t LCp[64 * CPW];
    __shared__ float sredS[128], sredQ[128];

    const int t = threadIdx.x, lane = t & 63, wid = t >> 6;
    const int b = blockIdx.y;
    const size_t bbase = (size_t)b * NCH * PSP;
    const int pbase = blockIdx.x * (64 * TPB);
    const int sb = b * NCH;                       // per-batch stats offset

    bf16x8 af[2][4];
    load_afrag16(w16, wid, lane, af);

    RawB16 rw;
    ld_raw_b16(x + bbase + pbase, rw);
    st_b16(STG[0], rw);
    __syncthreads();

    for (int i = 0; i < TPB; ++i) {
        const int cur = i & 1, nxt = cur ^ 1;
        const int pblk = pbase + i * 64;
        if (i + 1 < TPB) ld_raw_b16(x + bbase + pblk + 64, rw);
        f32x4 acc[2][4];
        zero_acc(acc);
        run_mfma(STG[cur], af, acc, lane);
        __syncthreads();                                    // a
        if (i + 1 < TPB) st_b16(STG[nxt], rw);
        write_LCp(LCp, acc, wid, lane);
        __syncthreads();                                    // b
        epi_store<false, true>(LCp, bpw, wout + bbase + pblk, sredS, sredQ);
        __syncthreads();                                    // c
        if (t < 128) { atomicAdd(&wsu[sb + t], sredS[t]); atomicAdd(&ws2[sb + t], sredQ[t]); }
    }
}

// ---------------------------------------------------------------------------
// G4: out = relu(Wpo * (norm(skip)*norm(weight)))
// ---------------------------------------------------------------------------
__global__ __launch_bounds__(256) void g4_kernel(
    const short* __restrict__ skip, const short* __restrict__ wgt,
    const float* __restrict__ sA, const float* __restrict__ sA2,
    const float* __restrict__ sB, const float* __restrict__ sB2,
    const short* __restrict__ w16, const float* __restrict__ bpo,
    short* __restrict__ outp)
{
    __shared__ __align__(16) uint32_t STG[2][64 * CPW];
    __shared__ __align__(16) uint32_t LCp[64 * CPW];
    __shared__ float nm[4][NCH];

    const int t = threadIdx.x, lane = t & 63, wid = t >> 6;
    const int b = blockIdx.y;
    const size_t bbase = (size_t)b * NCH * PSP;
    const int pbase = blockIdx.x * (64 * TPB);

    if (t < NCH) {
        float m = sA[b * NCH + t] * (1.0f / PSP);
        float v = sA2[b * NCH + t] * (1.0f / PSP) - m * m;
        nm[0][t] = m; nm[1][t] = rsqrtf(v + EPSV);
    } else {
        int c = t - NCH;
        float m = sB[b * NCH + c] * (1.0f / PSP);
        float v = sB2[b * NCH + c] * (1.0f / PSP) - m * m;
        nm[2][c] = m; nm[3][c] = rsqrtf(v + EPSV);
    }

    bf16x8 af[2][4];
    load_afrag16(w16, wid, lane, af);

    RawB16 rs, rw;
    ld_raw_b16(skip + bbase + pbase, rs);
    ld_raw_b16(wgt  + bbase + pbase, rw);
    __syncthreads();                 // nm ready
    st_g4(STG[0], rs, rw, nm);
    __syncthreads();

    for (int i = 0; i < TPB; ++i) {
        const int cur = i & 1, nxt = cur ^ 1;
        const int pblk = pbase + i * 64;
        if (i + 1 < TPB) {
            ld_raw_b16(skip + bbase + pblk + 64, rs);
            ld_raw_b16(wgt  + bbase + pblk + 64, rw);
        }
        f32x4 acc[2][4];
        zero_acc(acc);
        run_mfma(STG[cur], af, acc, lane);
        __syncthreads();                                    // a
        if (i + 1 < TPB) st_g4(STG[nxt], rs, rw, nm);
        write_LCp(LCp, acc, wid, lane);
        __syncthreads();                                    // b
        epi_store<true, false>(LCp, bpo, outp + bbase + pblk, nullptr, nullptr);
    }
}

// ---------------------------------------------------------------------------
// G56: final = out * tanh(Wg2 * relu(Wg1*out + bg1) + bg2)
// LCp aliased onto RT (extra barrier) -> 50.7KB LDS -> 3 blocks/CU.
// ---------------------------------------------------------------------------
__global__ __launch_bounds__(256) void g56_kernel(
    const short* __restrict__ outb, const short* __restrict__ w16g1,
    const float* __restrict__ bg1, const short* __restrict__ w16g2,
    const float* __restrict__ bg2, float* __restrict__ fin)
{
    __shared__ __align__(16) uint32_t STG[2][64 * CPW];
    __shared__ __align__(16) uint32_t RT[64 * CPW];   // relu1 tile, then LCp

    const int t = threadIdx.x, lane = t & 63, wid = t >> 6;
    const int b = blockIdx.y;
    const size_t bbase = (size_t)b * NCH * PSP;
    const int pbase = blockIdx.x * (64 * TPB);

    bf16x8 af1[2][4], af2[2][4];
    load_afrag16(w16g1, wid, lane, af1);
    load_afrag16(w16g2, wid, lane, af2);

    float bg1v[2][4];
    {
        const int og = wid * 32 + (lane >> 4) * 4;
        #pragma unroll
        for (int mt = 0; mt < 2; ++mt)
            #pragma unroll
            for (int r = 0; r < 4; ++r) bg1v[mt][r] = bg1[og + mt * 16 + r];
    }

    RawB16 rw;
    ld_raw_b16(outb + bbase + pbase, rw);
    st_b16(STG[0], rw);
    __syncthreads();

    for (int i = 0; i < TPB; ++i) {
        const int cur = i & 1, nxt = cur ^ 1;
        const int pblk = pbase + i * 64;
        if (i + 1 < TPB) ld_raw_b16(outb + bbase + pblk + 64, rw);
        f32x4 acc[2][4];
        zero_acc(acc);
        run_mfma(STG[cur], af1, acc, lane);
        __syncthreads();                                    // a
        // relu1 -> RT
        {
            const int l15 = lane & 15, og = wid * 32 + (lane >> 4) * 4;
            #pragma unroll
            for (int mt = 0; mt < 2; ++mt)
                #pragma unroll
                for (int nt = 0; nt < 4; ++nt) {
                    const int o2 = (og >> 1) + mt * 8, p = nt * 16 + l15;
                    f32x4 a = acc[mt][nt];
                    float z0 = fmaxf(a[0] + bg1v[mt][0], 0.0f);
                    float z1 = fmaxf(a[1] + bg1v[mt][1], 0.0f);
                    float z2 = fmaxf(a[2] + bg1v[mt][2], 0.0f);
                    float z3 = fmaxf(a[3] + bg1v[mt][3], 0.0f);
                    RT[o2 * CPW + p]       = pk2f(z0, z1);
                    RT[(o2 + 1) * CPW + p] = pk2f(z2, z3);
                }
        }
        if (i + 1 < TPB) st_b16(STG[nxt], rw);
        __syncthreads();                                    // b
        zero_acc(acc);
        run_mfma(RT, af2, acc, lane);
        __syncthreads();                                    // b2: all RT reads done
        write_LCp(RT, acc, wid, lane);
        __syncthreads();                                    // c
        // final epilogue: f32 = out * tanh(RT + bg2)
        {
            float* dst = fin + bbase + pblk;
            #pragma unroll
            for (int r = 0; r < 8; ++r) {
                const int u = r * 256 + t, o = u >> 4, ch = u & 15, hi = o & 1;
                const float bia = bg2[o];
                const uint32_t* lc = RT + (o >> 1) * CPW + ch * 4;
                const uint32_t* mg = STG[cur] + (o >> 1) * CPW + ch * 4;
                uint2 l0 = *(const uint2*)lc, l1 = *(const uint2*)(lc + 2);
                uint2 m0 = *(const uint2*)mg, m1 = *(const uint2*)(mg + 2);
                f32x4 ov;
                ov[0] = (hi ? bfHI(m0.x) : bfLO(m0.x)) * tanhf((hi ? bfHI(l0.x) : bfLO(l0.x)) + bia);
                ov[1] = (hi ? bfHI(m0.y) : bfLO(m0.y)) * tanhf((hi ? bfHI(l0.y) : bfLO(l0.y)) + bia);
                ov[2] = (hi ? bfHI(m1.x) : bfLO(m1.x)) * tanhf((hi ? bfHI(l1.x) : bfLO(l1.x)) + bia);
                ov[3] = (hi ? bfHI(m1.y) : bfLO(m1.y)) * tanhf((hi ? bfHI(l1.y) : bfLO(l1.y)) + bia);
                *(f32x4*)(dst + (size_t)o * PSP + ch * 4) = ov;
            }
        }
        __syncthreads();                                    // d: epilogue reads done
    }
}

// ---------------------------------------------------------------------------
// Attention v3: 64 positions/block, 256 threads; thread = (p = t&63, heads
// h0 = t>>6 and h0+4). kn/v/cb staged in LDS (broadcast reads); q tile staged
// coalesced into LDS, read into 16 regs, region reused for X tile; coalesced
// 1KB/wave copyout.
// ---------------------------------------------------------------------------
__global__ __launch_bounds__(256) void attn3_kernel(
    const short* __restrict__ qpre, const float* __restrict__ knb,
    const float* __restrict__ cbb, const float* __restrict__ vbuf,
    short* __restrict__ xout)
{
    __shared__ __align__(16) uint32_t QX[64 * 65];   // q tile, then X tile
    __shared__ float KN[2560], VV[2560], CB[160];

    const int t = threadIdx.x;
    const int b = blockIdx.y;
    const int pblk = blockIdx.x * 64;
    const size_t bbase = (size_t)b * NCH * PSP;

    // stage kn / vv / cb (small, reused by all threads)
    {
        const float* kn = knb + b * 2560;
        const float* vv = vbuf + b * 2560;
        #pragma unroll
        for (int e = t; e < 2560; e += 256) { KN[e] = kn[e]; VV[e] = vv[e]; }
        if (t < 160) CB[t] = cbb[b * 160 + t];
    }
    // stage q tile (128c x 64p) -> QX channel pairs, full-line coalesced
    {
        const int c2 = t >> 2, p0 = (t & 3) * 16;
        const short* s0 = qpre + bbase + (size_t)(2 * c2) * PSP + pblk + p0;
        bf16x8 a0 = *(const bf16x8*)s0,         a1 = *(const bf16x8*)(s0 + 8);
        bf16x8 b0 = *(const bf16x8*)(s0 + PSP), b1 = *(const bf16x8*)(s0 + PSP + 8);
        uint32_t w[16];
        #pragma unroll
        for (int k = 0; k < 8; ++k) { w[k] = pk2s(a0[k], b0[k]); w[8 + k] = pk2s(a1[k], b1[k]); }
        uint32_t* base = QX + c2 * 65 + p0;
        #pragma unroll
        for (int k = 0; k < 8; ++k) *(uint2*)(base + 2 * k) = make_uint2(w[2 * k], w[2 * k + 1]);
    }
    __syncthreads();

    const int p = t & 63, h0 = t >> 6;
    uint32_t qw[16];
    #pragma unroll
    for (int i = 0; i < 8; ++i) {
        qw[i]     = QX[(h0 * 8 + i) * 65 + p];
        qw[8 + i] = QX[((h0 + 4) * 8 + i) * 65 + p];
    }
    __syncthreads();                 // QX region free -> X tile

    #pragma unroll 1
    for (int hh = 0; hh < 2; ++hh) {
        const int h = h0 + hh * 4;
        const int c0 = h * 16;
        float sim[20];
        #pragma unroll
        for (int l = 0; l < 20; ++l) sim[l] = -CB[h * 20 + l];
        #pragma unroll
        for (int i = 0; i < 8; ++i) {
            const uint32_t w = qw[hh * 8 + i];
            const float qlo = bfLO(w), qhi = bfHI(w);
            const float* k0 = KN + (c0 + 2 * i) * 20;
            #pragma unroll
            for (int l = 0; l < 20; ++l)
                sim[l] = fmaf(qlo, k0[l], fmaf(qhi, k0[20 + l], sim[l]));
        }
        float mx = sim[0];
        #pragma unroll
        for (int l = 1; l < 20; ++l) mx = fmaxf(mx, sim[l]);
        float se = 0.0f;
        #pragma unroll
        for (int l = 0; l < 20; ++l) { float e = __expf(sim[l] - mx); sim[l] = e; se += e; }
        const float inv = 1.0f / se;
        #pragma unroll
        for (int i = 0; i < 8; ++i) {
            const float* v0 = VV + (c0 + 2 * i) * 20;
            float x0 = 0.0f, x1 = 0.0f;
            #pragma unroll
            for (int l = 0; l < 20; ++l) {
                x0 = fmaf(sim[l], v0[l], x0);
                x1 = fmaf(sim[l], v0[20 + l], x1);
            }
            QX[p * 65 + h * 8 + i] = pk2f(x0 * inv, x1 * inv);
        }
    }
    __syncthreads();

    // coalesced copyout: wave writes 4 positions x 256B = 1KB contiguous
    {
        const int lane = t & 63, w = t >> 6;
        uint32_t* gdst = (uint32_t*)(xout + bbase + (size_t)pblk * NCH);
        #pragma unroll
        for (int j = 0; j < 4; ++j) {
            const int pp = w * 4 + j * 16 + (lane >> 4);
            const int cw = (lane & 15) * 4;
            const uint32_t* s = QX + pp * 65 + cw;
            *(uint4*)(gdst + pp * 64 + cw) = make_uint4(s[0], s[1], s[2], s[3]);
        }
    }
}

// ---------------------------------------------------------------------------
extern "C" void kernel_launch(void* const* d_in, const int* in_sizes, int n_in,
                              void* d_out, int out_size, void* d_ws, size_t ws_size,
                              hipStream_t stream)
{
    const float* img  = (const float*)d_in[0];
    const float* lang = (const float*)d_in[1];
    const float* Wq   = (const float*)d_in[2];
    const float* bq   = (const float*)d_in[3];
    const float* Wk   = (const float*)d_in[4];
    const float* bk   = (const float*)d_in[5];
    const float* Wv   = (const float*)d_in[6];
    const float* bv   = (const float*)d_in[7];
    const float* Wpw  = (const float*)d_in[8];
    const float* bpw  = (const float*)d_in[9];
    const float* Wpi  = (const float*)d_in[10];
    const float* bpi  = (const float*)d_in[11];
    const float* Wpo  = (const float*)d_in[12];
    const float* bpo  = (const float*)d_in[13];
    const float* Wg1  = (const float*)d_in[14];
    const float* bg1  = (const float*)d_in[15];
    const float* Wg2  = (const float*)d_in[16];
    const float* bg2  = (const float*)d_in[17];
    float* outp = (float*)d_out;

    const size_t N = (size_t)NB * NCH * PSP;
    const size_t needed = 3 * N * sizeof(short) + 6 * NCH * NCH * sizeof(short)
                        + (3 * 2 * 2560 + 2 * 160 + 6 * 256) * sizeof(float);
    if (ws_size < needed) return;

    short* bufA = (short*)d_ws;          // q_pre, then weight_pre
    short* bufB = bufA + N;              // x, then 'out'
    short* bufC = bufB + N;              // skip_pre
    short* wt16 = bufC + N;              // 6 x 128x128 bf16 weights
    float* kbuf = (float*)(wt16 + 6 * NCH * NCH);
    float* vbuf = kbuf + 2 * 2560;
    float* knb  = vbuf + 2 * 2560;
    float* cbb  = knb + 2 * 2560;
    float* st   = cbb + 2 * 160;
    float* qs   = st;
    float* qs2  = st + 256;
    float* ss   = st + 512;
    float* ss2  = st + 768;
    float* wsu  = st + 1024;
    float* ws2  = st + 1280;

    hipMemsetAsync(st, 0, 6 * 256 * sizeof(float), stream);
    kv_kernel<<<dim3(40), dim3(256), 0, stream>>>(lang, Wk, bk, Wv, bv, kbuf, vbuf);
    // order in wt16: Wq, Wpi, Wpw, Wpo, Wg1, Wg2
    wprep_kernel<<<dim3(96), dim3(256), 0, stream>>>(Wq, Wpi, Wpw, Wpo, Wg1, Wg2, wt16);

    const dim3 gg(PSP / (64 * TPB), NB), gb(256);

    // q_pre -> bufA, skip_pre -> bufC (img read once)
    g12_kernel<<<gg, gb, 0, stream>>>(img, wt16, bq, bpi, bufA, bufC, qs, qs2, ss, ss2);
    // kn / cb from q stats + k
    knprep_kernel<<<dim3(NB), dim3(256), 0, stream>>>(qs, qs2, kbuf, knb, cbb);
    // attention: q_pre -> x (bufB), flat (b,p,c) order == x_img c-major
    attn3_kernel<<<dim3(PSP / 64, NB), gb, 0, stream>>>(bufA, knb, cbb, vbuf, bufB);
    // weight_pre = Wpw * x (+stats) -> bufA
    g3_kernel<<<gg, gb, 0, stream>>>(bufB, wt16 + 2 * NCH * NCH, bpw, bufA, wsu, ws2);
    // out = relu(Wpo*(norm(skip)*norm(weight))) -> bufB
    g4_kernel<<<gg, gb, 0, stream>>>(bufC, bufA, ss, ss2, wsu, ws2,
                                     wt16 + 3 * NCH * NCH, bpo, bufB);
    // final -> d_out
    g56_kernel<<<gg, gb, 0, stream>>>(bufB, wt16 + 4 * NCH * NCH, bg1,
                                      wt16 + 5 * NCH * NCH, bg2, outp);
}

// Round 8
// 322.206 us; speedup vs baseline: 4.0186x; 1.1143x over previous
//
#include <hip/hip_runtime.h>
#include <cstdint>
#include <cstddef>

#define PSP 110592          // 48*48*48 positions per batch
#define NCH 128
#define NB  2
#define CPW 68              // u32 stride of LCp rows (64 + 4 pad -> 2-way max)
#define TPB 4               // 64-pos tiles per GEMM block
static constexpr float EPSV = 1e-5f;

typedef short bf16x8 __attribute__((ext_vector_type(8)));
typedef float f32x4  __attribute__((ext_vector_type(4)));

static __device__ __forceinline__ short f2bf(float f) {
    uint32_t u = __builtin_bit_cast(uint32_t, f);
    u += 0x7FFF + ((u >> 16) & 1);          // RNE
    return (short)(u >> 16);
}
static __device__ __forceinline__ float bf2f(short s) {
    uint32_t u = ((uint32_t)(uint16_t)s) << 16;
    return __builtin_bit_cast(float, u);
}
static __device__ __forceinline__ float bfLO(uint32_t w) { return bf2f((short)(w & 0xffff)); }
static __device__ __forceinline__ float bfHI(uint32_t w) { return bf2f((short)(w >> 16)); }
static __device__ __forceinline__ uint32_t pk2f(float lo, float hi) {
    return (uint32_t)(uint16_t)f2bf(lo) | ((uint32_t)(uint16_t)f2bf(hi) << 16);
}
static __device__ __forceinline__ uint32_t pk2s(short lo, short hi) {
    return (uint32_t)(uint16_t)lo | ((uint32_t)(uint16_t)hi << 16);
}
static __device__ __forceinline__ int swzb(int p) {
    return (((p & 7) ^ ((p >> 3) & 7)) << 4);
}

// ---------------------------------------------------------------------------
// tiny kernels
// ---------------------------------------------------------------------------
__global__ __launch_bounds__(256) void kv_kernel(
    const float* __restrict__ lang,
    const float* __restrict__ Wk, const float* __restrict__ bk,
    const float* __restrict__ Wv, const float* __restrict__ bv,
    float* __restrict__ kout, float* __restrict__ vout)
{
    int gid = blockIdx.x * 256 + threadIdx.x;     // 0..10239
    int sel = gid / 5120;
    int r   = gid % 5120;
    int b   = r / 2560;
    int o   = (r % 2560) / 20;
    int l   = r % 20;
    const float* W  = sel ? Wv : Wk;
    const float* bb = sel ? bv : bk;
    const float* lg = lang + b * 256 * 20 + l;
    float acc = bb[o];
    #pragma unroll 8
    for (int c = 0; c < 256; ++c)
        acc = fmaf(W[o * 256 + c], lg[c * 20], acc);
    (sel ? vout : kout)[b * 2560 + o * 20 + l] = acc;
}

__global__ __launch_bounds__(256) void wprep_kernel(
    const float* __restrict__ w0, const float* __restrict__ w1,
    const float* __restrict__ w2, const float* __restrict__ w3,
    const float* __restrict__ w4, const float* __restrict__ w5,
    short* __restrict__ wt)
{
    const int m = blockIdx.x >> 4, s = blockIdx.x & 15;
    const float* src = w0;
    if (m == 1) src = w1; else if (m == 2) src = w2; else if (m == 3) src = w3;
    else if (m == 4) src = w4; else if (m == 5) src = w5;
    short* dst = wt + m * NCH * NCH;
    const int i0 = s * 1024 + threadIdx.x * 4;
    f32x4 v = *(const f32x4*)(src + i0);
    *(uint2*)(dst + i0) = make_uint2(pk2f(v[0], v[1]) /*lo=v0,hi=v1*/,
                                     pk2f(v[2], v[3]));
}

__global__ __launch_bounds__(256) void knprep_kernel(
    const float* __restrict__ qs, const float* __restrict__ qs2,
    const float* __restrict__ kbuf,
    float* __restrict__ knb, float* __restrict__ cbb)
{
    __shared__ float mq[128], rqs[128], knl[2560];
    const int t = threadIdx.x, b = blockIdx.x;
    if (t < 128) {
        float m = qs[b * 128 + t] * (1.0f / PSP);
        float v = qs2[b * 128 + t] * (1.0f / PSP) - m * m;
        mq[t] = m;
        rqs[t] = rsqrtf(v + EPSV) * 0.25f;
    }
    __syncthreads();
    for (int e = t; e < 2560; e += 256) {
        int c = e / 20;
        float kv = rqs[c] * kbuf[b * 2560 + e];
        knl[e] = kv;
        knb[b * 2560 + e] = kv;
    }
    __syncthreads();
    if (t < 160) {
        int h = t / 20, l = t % 20;
        float s = 0.0f;
        #pragma unroll
        for (int i = 0; i < 16; ++i)
            s = fmaf(mq[h * 16 + i], knl[(h * 16 + i) * 20 + l], s);
        cbb[b * 160 + t] = s;
    }
}

// ---------------------------------------------------------------------------
// GEMM building blocks — STG layout: bf16 [64 p][128 c], byte = p*256 + c*2,
// XOR-swizzled by swzb(p). Thread u owns channels 4*(u>>3).. +3, pos (u&7)*8 +0..7.
// ---------------------------------------------------------------------------
struct PackW { uint32_t lo[8], hi[8]; };   // per j: lo=(c,c+1), hi=(c+2,c+3)

static __device__ __forceinline__ void ldpack_f32(const float* src, PackW& w) {
    const int t = threadIdx.x;
    const float* s = src + (size_t)(4 * (t >> 3)) * PSP + (t & 7) * 8;
    f32x4 r0a = *(const f32x4*)s,             r0b = *(const f32x4*)(s + 4);
    f32x4 r1a = *(const f32x4*)(s + PSP),     r1b = *(const f32x4*)(s + PSP + 4);
    f32x4 r2a = *(const f32x4*)(s + 2 * PSP), r2b = *(const f32x4*)(s + 2 * PSP + 4);
    f32x4 r3a = *(const f32x4*)(s + 3 * PSP), r3b = *(const f32x4*)(s + 3 * PSP + 4);
    #pragma unroll
    for (int j = 0; j < 4; ++j) {
        w.lo[j]     = pk2f(r0a[j], r1a[j]);
        w.lo[4 + j] = pk2f(r0b[j], r1b[j]);
        w.hi[j]     = pk2f(r2a[j], r3a[j]);
        w.hi[4 + j] = pk2f(r2b[j], r3b[j]);
    }
}
static __device__ __forceinline__ void ldpack_b16(const short* src, PackW& w) {
    const int t = threadIdx.x;
    const short* s = src + (size_t)(4 * (t >> 3)) * PSP + (t & 7) * 8;
    bf16x8 r0 = *(const bf16x8*)s;
    bf16x8 r1 = *(const bf16x8*)(s + PSP);
    bf16x8 r2 = *(const bf16x8*)(s + 2 * PSP);
    bf16x8 r3 = *(const bf16x8*)(s + 3 * PSP);
    #pragma unroll
    for (int j = 0; j < 8; ++j) { w.lo[j] = pk2s(r0[j], r1[j]); w.hi[j] = pk2s(r2[j], r3[j]); }
}
static __device__ __forceinline__ void ldpack_g4(const short* skip, const short* wgt,
        const float nm[4][NCH], PackW& w) {
    const int t = threadIdx.x;
    const int c = 4 * (t >> 3), p0 = (t & 7) * 8;
    const short* s = skip + (size_t)c * PSP + p0;
    const short* g = wgt  + (size_t)c * PSP + p0;
    bf16x8 s0 = *(const bf16x8*)s,             s1 = *(const bf16x8*)(s + PSP);
    bf16x8 s2 = *(const bf16x8*)(s + 2 * PSP), s3 = *(const bf16x8*)(s + 3 * PSP);
    bf16x8 g0 = *(const bf16x8*)g,             g1 = *(const bf16x8*)(g + PSP);
    bf16x8 g2 = *(const bf16x8*)(g + 2 * PSP), g3 = *(const bf16x8*)(g + 3 * PSP);
    float mA[4], rA[4], mB[4], rB[4];
    #pragma unroll
    for (int r = 0; r < 4; ++r) {
        mA[r] = nm[0][c + r]; rA[r] = nm[1][c + r];
        mB[r] = nm[2][c + r]; rB[r] = nm[3][c + r];
    }
    #pragma unroll
    for (int j = 0; j < 8; ++j) {
        float v0 = ((bf2f(s0[j]) - mA[0]) * rA[0]) * ((bf2f(g0[j]) - mB[0]) * rB[0]);
        float v1 = ((bf2f(s1[j]) - mA[1]) * rA[1]) * ((bf2f(g1[j]) - mB[1]) * rB[1]);
        float v2 = ((bf2f(s2[j]) - mA[2]) * rA[2]) * ((bf2f(g2[j]) - mB[2]) * rB[2]);
        float v3 = ((bf2f(s3[j]) - mA[3]) * rA[3]) * ((bf2f(g3[j]) - mB[3]) * rB[3]);
        w.lo[j] = pk2f(v0, v1);
        w.hi[j] = pk2f(v2, v3);
    }
}
static __device__ __forceinline__ void stage(char* STGb, const PackW& w) {
    const int t = threadIdx.x;
    const int c8 = (t >> 3) * 8, p0 = (t & 7) * 8;
    #pragma unroll
    for (int j = 0; j < 8; ++j) {
        int byte = (p0 + j) * 256 + c8;
        byte ^= ((j ^ (t & 7)) << 4);
        *(uint2*)(STGb + byte) = make_uint2(w.lo[j], w.hi[j]);
    }
}

static __device__ __forceinline__ void load_afrag16(const short* __restrict__ W16,
                                                    int wid, int lane, bf16x8 af[2][4]) {
    const int orow = wid * 32 + (lane & 15);
    const int cb   = (lane >> 4) * 8;
    #pragma unroll
    for (int mt = 0; mt < 2; ++mt)
        #pragma unroll
        for (int kt = 0; kt < 4; ++kt)
            af[mt][kt] = *(const bf16x8*)(W16 + (size_t)(orow + mt * 16) * NCH + kt * 32 + cb);
}

static __device__ __forceinline__ void run_mfmaX(const char* STGb, const bf16x8 af[2][4],
                                                 f32x4 acc[2][4], int lane) {
    const int l15 = lane & 15, kh = lane >> 4;
    #pragma unroll
    for (int nt = 0; nt < 4; ++nt) {
        const int p = nt * 16 + l15;
        const int sw = swzb(p);
        bf16x8 bf[4];
        #pragma unroll
        for (int kt = 0; kt < 4; ++kt)
            bf[kt] = *(const bf16x8*)(STGb + ((p * 256 + kt * 64 + kh * 16) ^ sw));
        #pragma unroll
        for (int kt = 0; kt < 4; ++kt) {
            acc[0][nt] = __builtin_amdgcn_mfma_f32_16x16x32_bf16(af[0][kt], bf[kt], acc[0][nt], 0, 0, 0);
            acc[1][nt] = __builtin_amdgcn_mfma_f32_16x16x32_bf16(af[1][kt], bf[kt], acc[1][nt], 0, 0, 0);
        }
    }
}
static __device__ __forceinline__ void zero_acc(f32x4 acc[2][4]) {
    #pragma unroll
    for (int m = 0; m < 2; ++m)
        #pragma unroll
        for (int n = 0; n < 4; ++n) acc[m][n] = (f32x4)0.0f;
}
static __device__ __forceinline__ void write_LCp(uint32_t* LCp, const f32x4 acc[2][4],
                                                 int wid, int lane) {
    const int l15 = lane & 15, og = wid * 32 + (lane >> 4) * 4;
    #pragma unroll
    for (int mt = 0; mt < 2; ++mt)
        #pragma unroll
        for (int nt = 0; nt < 4; ++nt) {
            const int o2 = (og >> 1) + mt * 8, p = nt * 16 + l15;
            f32x4 a = acc[mt][nt];
            LCp[o2 * CPW + p]       = pk2f(a[0], a[1]);
            LCp[(o2 + 1) * CPW + p] = pk2f(a[2], a[3]);
        }
}
// epilogue: unpack LCp (uint4 conflict-free reads), +bias (+relu), coalesced
// bf16 store; stats accumulated in caller registers.
template<bool RELU, bool STATS>
static __device__ __forceinline__ void epi2(const uint32_t* LCp, const float* __restrict__ bias,
        short* __restrict__ dst, float sS[4], float sQ[4])
{
    const int t = threadIdx.x;
    #pragma unroll
    for (int r = 0; r < 4; ++r) {
        const int u = r * 256 + t, o = u >> 3, ch = u & 7, hi = o & 1;
        const float bia = bias[o];
        const uint32_t* src = LCp + (o >> 1) * CPW + ch * 8;
        uint4 wa = *(const uint4*)src;
        uint4 wb = *(const uint4*)(src + 4);
        uint32_t ww[8] = {wa.x, wa.y, wa.z, wa.w, wb.x, wb.y, wb.z, wb.w};
        float v[8];
        #pragma unroll
        for (int j = 0; j < 8; ++j) v[j] = (hi ? bfHI(ww[j]) : bfLO(ww[j])) + bia;
        if (RELU) {
            #pragma unroll
            for (int j = 0; j < 8; ++j) v[j] = fmaxf(v[j], 0.0f);
        }
        bf16x8 s8;
        #pragma unroll
        for (int j = 0; j < 8; ++j) s8[j] = f2bf(v[j]);
        *(bf16x8*)(dst + (size_t)o * PSP + ch * 8) = s8;
        if (STATS) {
            float s = 0.0f, q = 0.0f;
            #pragma unroll
            for (int j = 0; j < 8; ++j) { s += v[j]; q += v[j] * v[j]; }
            sS[r] += s; sQ[r] += q;
        }
    }
}
static __device__ __forceinline__ void flush_stats(const float sS[4], const float sQ[4],
        float* __restrict__ s_sum, float* __restrict__ s_sq)
{
    const int t = threadIdx.x;
    #pragma unroll
    for (int r = 0; r < 4; ++r) {
        float s = sS[r], q = sQ[r];
        s += __shfl_xor(s, 1); q += __shfl_xor(q, 1);
        s += __shfl_xor(s, 2); q += __shfl_xor(q, 2);
        s += __shfl_xor(s, 4); q += __shfl_xor(q, 4);
        if ((t & 7) == 0) {
            atomicAdd(&s_sum[r * 32 + (t >> 3)], s);
            atomicAdd(&s_sq [r * 32 + (t >> 3)], q);
        }
    }
}

// ---------------------------------------------------------------------------
// G12: q_pre = Wq*img (+stats) and skip_pre = Wpi*img (+stats); img read once.
// ---------------------------------------------------------------------------
__global__ __launch_bounds__(256) void g12_kernel(
    const float* __restrict__ img, const short* __restrict__ w16,
    const float* __restrict__ bq, const float* __restrict__ bpi,
    short* __restrict__ qout, short* __restrict__ sout,
    float* __restrict__ qs, float* __restrict__ qs2,
    float* __restrict__ ss, float* __restrict__ ss2)
{
    __shared__ __align__(16) char STGb[16384];
    __shared__ __align__(16) uint32_t LCp[64 * CPW];

    const int t = threadIdx.x, lane = t & 63, wid = t >> 6;
    const int b = blockIdx.y;
    const size_t bbase = (size_t)b * NCH * PSP;
    const int pbase = blockIdx.x * (64 * TPB);
    const int sb = b * NCH;

    bf16x8 afq[2][4], afp[2][4];
    load_afrag16(w16, wid, lane, afq);
    load_afrag16(w16 + NCH * NCH, wid, lane, afp);

    float qS[4] = {0, 0, 0, 0}, qQ[4] = {0, 0, 0, 0};
    float sS[4] = {0, 0, 0, 0}, sQ[4] = {0, 0, 0, 0};

    PackW w;
    ldpack_f32(img + bbase + pbase, w);

    for (int i = 0; i < TPB; ++i) {
        const int pblk = pbase + i * 64;
        stage(STGb, w);
        __syncthreads();                                    // A: STG ready
        if (i + 1 < TPB) ldpack_f32(img + bbase + pblk + 64, w);
        f32x4 acc[2][4];
        zero_acc(acc);
        run_mfmaX(STGb, afq, acc, lane);
        write_LCp(LCp, acc, wid, lane);
        __syncthreads();                                    // B: LCp(q) ready
        epi2<false, true>(LCp, bq, qout + bbase + pblk, qS, qQ);
        zero_acc(acc);
        run_mfmaX(STGb, afp, acc, lane);
        __syncthreads();                                    // C: LCp reads + STG reads done
        write_LCp(LCp, acc, wid, lane);
        __syncthreads();                                    // D: LCp(p) ready
        epi2<false, true>(LCp, bpi, sout + bbase + pblk, sS, sQ);
        // loop: stage overwrites STG (reads done @C); next write_LCp after next B>=A
    }
    flush_stats(qS, qQ, qs + sb, qs2 + sb);
    flush_stats(sS, sQ, ss + sb, ss2 + sb);
}

// ---------------------------------------------------------------------------
// G3: weight_pre = Wpw * x (+stats)
// ---------------------------------------------------------------------------
__global__ __launch_bounds__(256) void g3_kernel(
    const short* __restrict__ x, const short* __restrict__ w16,
    const float* __restrict__ bpw, short* __restrict__ wout,
    float* __restrict__ wsu, float* __restrict__ ws2)
{
    __shared__ __align__(16) char STGb[16384];
    __shared__ __align__(16) uint32_t LCp[64 * CPW];

    const int t = threadIdx.x, lane = t & 63, wid = t >> 6;
    const int b = blockIdx.y;
    const size_t bbase = (size_t)b * NCH * PSP;
    const int pbase = blockIdx.x * (64 * TPB);
    const int sb = b * NCH;

    bf16x8 af[2][4];
    load_afrag16(w16, wid, lane, af);
    float wS[4] = {0, 0, 0, 0}, wQ[4] = {0, 0, 0, 0};

    PackW w;
    ldpack_b16(x + bbase + pbase, w);

    for (int i = 0; i < TPB; ++i) {
        const int pblk = pbase + i * 64;
        stage(STGb, w);
        __syncthreads();                                    // A
        if (i + 1 < TPB) ldpack_b16(x + bbase + pblk + 64, w);
        f32x4 acc[2][4];
        zero_acc(acc);
        run_mfmaX(STGb, af, acc, lane);
        write_LCp(LCp, acc, wid, lane);
        __syncthreads();                                    // B
        epi2<false, true>(LCp, bpw, wout + bbase + pblk, wS, wQ);
    }
    flush_stats(wS, wQ, wsu + sb, ws2 + sb);
}

// ---------------------------------------------------------------------------
// G4: out = relu(Wpo * (norm(skip)*norm(weight)))
// ---------------------------------------------------------------------------
__global__ __launch_bounds__(256) void g4_kernel(
    const short* __restrict__ skip, const short* __restrict__ wgt,
    const float* __restrict__ sA, const float* __restrict__ sA2,
    const float* __restrict__ sB, const float* __restrict__ sB2,
    const short* __restrict__ w16, const float* __restrict__ bpo,
    short* __restrict__ outp)
{
    __shared__ __align__(16) char STGb[16384];
    __shared__ __align__(16) uint32_t LCp[64 * CPW];
    __shared__ float nm[4][NCH];

    const int t = threadIdx.x, lane = t & 63, wid = t >> 6;
    const int b = blockIdx.y;
    const size_t bbase = (size_t)b * NCH * PSP;
    const int pbase = blockIdx.x * (64 * TPB);

    if (t < NCH) {
        float m = sA[b * NCH + t] * (1.0f / PSP);
        float v = sA2[b * NCH + t] * (1.0f / PSP) - m * m;
        nm[0][t] = m; nm[1][t] = rsqrtf(v + EPSV);
    } else {
        int c = t - NCH;
        float m = sB[b * NCH + c] * (1.0f / PSP);
        float v = sB2[b * NCH + c] * (1.0f / PSP) - m * m;
        nm[2][c] = m; nm[3][c] = rsqrtf(v + EPSV);
    }
    bf16x8 af[2][4];
    load_afrag16(w16, wid, lane, af);
    __syncthreads();                 // nm ready

    PackW w;
    ldpack_g4(skip + bbase + pbase, wgt + bbase + pbase, nm, w);
    float dS[4], dQ[4];              // unused (no stats)

    for (int i = 0; i < TPB; ++i) {
        const int pblk = pbase + i * 64;
        stage(STGb, w);
        __syncthreads();                                    // A
        if (i + 1 < TPB)
            ldpack_g4(skip + bbase + pblk + 64, wgt + bbase + pblk + 64, nm, w);
        f32x4 acc[2][4];
        zero_acc(acc);
        run_mfmaX(STGb, af, acc, lane);
        write_LCp(LCp, acc, wid, lane);
        __syncthreads();                                    // B
        epi2<true, false>(LCp, bpo, outp + bbase + pblk, dS, dQ);
    }
}

// ---------------------------------------------------------------------------
// G56: final = out * tanh(Wg2 * relu(Wg1*out + bg1) + bg2)
// RTL region holds relu1 tile ([p][c] swz, 16KB) then LCp (17.4KB).
// ---------------------------------------------------------------------------
__global__ __launch_bounds__(256) void g56_kernel(
    const short* __restrict__ outb, const short* __restrict__ w16g1,
    const float* __restrict__ bg1, const short* __restrict__ w16g2,
    const float* __restrict__ bg2, float* __restrict__ fin)
{
    __shared__ __align__(16) char STGb[16384];
    __shared__ __align__(16) char RTL[64 * CPW * 4];   // relu1 [p][c], then LCp

    const int t = threadIdx.x, lane = t & 63, wid = t >> 6;
    const int b = blockIdx.y;
    const size_t bbase = (size_t)b * NCH * PSP;
    const int pbase = blockIdx.x * (64 * TPB);

    bf16x8 af1[2][4], af2[2][4];
    load_afrag16(w16g1, wid, lane, af1);
    load_afrag16(w16g2, wid, lane, af2);

    float bg1v[2][4];
    {
        const int og = wid * 32 + (lane >> 4) * 4;
        #pragma unroll
        for (int mt = 0; mt < 2; ++mt)
            #pragma unroll
            for (int r = 0; r < 4; ++r) bg1v[mt][r] = bg1[og + mt * 16 + r];
    }

    PackW w;
    ldpack_b16(outb + bbase + pbase, w);

    for (int i = 0; i < TPB; ++i) {
        const int pblk = pbase + i * 64;
        stage(STGb, w);
        __syncthreads();                                    // A: STG ready
        if (i + 1 < TPB) ldpack_b16(outb + bbase + pblk + 64, w);
        f32x4 acc[2][4];
        zero_acc(acc);
        run_mfmaX(STGb, af1, acc, lane);
        // relu1 -> RTL as [p][c] swizzled bf16
        {
            const int l15 = lane & 15, og = wid * 32 + (lane >> 4) * 4;
            #pragma unroll
            for (int mt = 0; mt < 2; ++mt)
                #pragma unroll
                for (int nt = 0; nt < 4; ++nt) {
                    const int o = og + mt * 16, p = nt * 16 + l15;
                    const int sw = swzb(p);
                    f32x4 a = acc[mt][nt];
                    float z0 = fmaxf(a[0] + bg1v[mt][0], 0.0f);
                    float z1 = fmaxf(a[1] + bg1v[mt][1], 0.0f);
                    float z2 = fmaxf(a[2] + bg1v[mt][2], 0.0f);
                    float z3 = fmaxf(a[3] + bg1v[mt][3], 0.0f);
                    *(uint32_t*)(RTL + ((p * 256 + o * 2) ^ sw))     = pk2f(z0, z1);
                    *(uint32_t*)(RTL + ((p * 256 + o * 2 + 4) ^ sw)) = pk2f(z2, z3);
                }
        }
        __syncthreads();                                    // B: RT ready
        zero_acc(acc);
        run_mfmaX(RTL, af2, acc, lane);
        __syncthreads();                                    // C: RT reads done
        write_LCp((uint32_t*)RTL, acc, wid, lane);
        __syncthreads();                                    // D: LCp ready
        // final epilogue: f32 = out * tanh(LCp + bg2)
        {
            const uint32_t* LCp = (const uint32_t*)RTL;
            float* dst = fin + bbase + pblk;
            #pragma unroll
            for (int r = 0; r < 4; ++r) {
                const int u = r * 256 + t, o2 = u >> 4, ch = u & 15;
                const float b0 = bg2[2 * o2], b1 = bg2[2 * o2 + 1];
                uint4 lc = *(const uint4*)(LCp + o2 * CPW + ch * 4);
                uint32_t lw[4] = {lc.x, lc.y, lc.z, lc.w};
                f32x4 oA, oB;
                #pragma unroll
                for (int j = 0; j < 4; ++j) {
                    const int p = ch * 4 + j;
                    uint32_t mw = *(const uint32_t*)(STGb + ((p * 256 + o2 * 4) ^ swzb(p)));
                    oA[j] = bfLO(mw) * tanhf(bfLO(lw[j]) + b0);
                    oB[j] = bfHI(mw) * tanhf(bfHI(lw[j]) + b1);
                }
                *(f32x4*)(dst + (size_t)(2 * o2) * PSP + ch * 4)     = oA;
                *(f32x4*)(dst + (size_t)(2 * o2 + 1) * PSP + ch * 4) = oB;
            }
        }
        __syncthreads();                                    // E: STG/LCp reads done
    }
}

// ---------------------------------------------------------------------------
// Attention v3 (round-7 proven): 64 positions/block; kn/v/cb in LDS;
// q tile staged coalesced; X tile reuses q region; coalesced copyout.
// ---------------------------------------------------------------------------
__global__ __launch_bounds__(256) void attn3_kernel(
    const short* __restrict__ qpre, const float* __restrict__ knb,
    const float* __restrict__ cbb, const float* __restrict__ vbuf,
    short* __restrict__ xout)
{
    __shared__ __align__(16) uint32_t QX[64 * 65];   // q tile, then X tile
    __shared__ float KN[2560], VV[2560], CB[160];

    const int t = threadIdx.x;
    const int b = blockIdx.y;
    const int pblk = blockIdx.x * 64;
    const size_t bbase = (size_t)b * NCH * PSP;

    {
        const float* kn = knb + b * 2560;
        const float* vv = vbuf + b * 2560;
        #pragma unroll
        for (int e = t; e < 2560; e += 256) { KN[e] = kn[e]; VV[e] = vv[e]; }
        if (t < 160) CB[t] = cbb[b * 160 + t];
    }
    {
        const int c2 = t >> 2, p0 = (t & 3) * 16;
        const short* s0 = qpre + bbase + (size_t)(2 * c2) * PSP + pblk + p0;
        bf16x8 a0 = *(const bf16x8*)s0,         a1 = *(const bf16x8*)(s0 + 8);
        bf16x8 b0 = *(const bf16x8*)(s0 + PSP), b1 = *(const bf16x8*)(s0 + PSP + 8);
        uint32_t w[16];
        #pragma unroll
        for (int k = 0; k < 8; ++k) { w[k] = pk2s(a0[k], b0[k]); w[8 + k] = pk2s(a1[k], b1[k]); }
        uint32_t* base = QX + c2 * 65 + p0;
        #pragma unroll
        for (int k = 0; k < 8; ++k) *(uint2*)(base + 2 * k) = make_uint2(w[2 * k], w[2 * k + 1]);
    }
    __syncthreads();

    const int p = t & 63, h0 = t >> 6;
    uint32_t qw[16];
    #pragma unroll
    for (int i = 0; i < 8; ++i) {
        qw[i]     = QX[(h0 * 8 + i) * 65 + p];
        qw[8 + i] = QX[((h0 + 4) * 8 + i) * 65 + p];
    }
    __syncthreads();

    #pragma unroll 1
    for (int hh = 0; hh < 2; ++hh) {
        const int h = h0 + hh * 4;
        const int c0 = h * 16;
        float sim[20];
        #pragma unroll
        for (int l = 0; l < 20; ++l) sim[l] = -CB[h * 20 + l];
        #pragma unroll
        for (int i = 0; i < 8; ++i) {
            const uint32_t w = qw[hh * 8 + i];
            const float qlo = bfLO(w), qhi = bfHI(w);
            const float* k0 = KN + (c0 + 2 * i) * 20;
            #pragma unroll
            for (int l = 0; l < 20; ++l)
                sim[l] = fmaf(qlo, k0[l], fmaf(qhi, k0[20 + l], sim[l]));
        }
        float mx = sim[0];
        #pragma unroll
        for (int l = 1; l < 20; ++l) mx = fmaxf(mx, sim[l]);
        float se = 0.0f;
        #pragma unroll
        for (int l = 0; l < 20; ++l) { float e = __expf(sim[l] - mx); sim[l] = e; se += e; }
        const float inv = 1.0f / se;
        #pragma unroll
        for (int i = 0; i < 8; ++i) {
            const float* v0 = VV + (c0 + 2 * i) * 20;
            float x0 = 0.0f, x1 = 0.0f;
            #pragma unroll
            for (int l = 0; l < 20; ++l) {
                x0 = fmaf(sim[l], v0[l], x0);
                x1 = fmaf(sim[l], v0[20 + l], x1);
            }
            QX[p * 65 + h * 8 + i] = pk2f(x0 * inv, x1 * inv);
        }
    }
    __syncthreads();

    {
        const int lane = t & 63, w = t >> 6;
        uint32_t* gdst = (uint32_t*)(xout + bbase + (size_t)pblk * NCH);
        #pragma unroll
        for (int j = 0; j < 4; ++j) {
            const int pp = w * 4 + j * 16 + (lane >> 4);
            const int cw = (lane & 15) * 4;
            const uint32_t* s = QX + pp * 65 + cw;
            *(uint4*)(gdst + pp * 64 + cw) = make_uint4(s[0], s[1], s[2], s[3]);
        }
    }
}

// ---------------------------------------------------------------------------
extern "C" void kernel_launch(void* const* d_in, const int* in_sizes, int n_in,
                              void* d_out, int out_size, void* d_ws, size_t ws_size,
                              hipStream_t stream)
{
    const float* img  = (const float*)d_in[0];
    const float* lang = (const float*)d_in[1];
    const float* Wq   = (const float*)d_in[2];
    const float* bq   = (const float*)d_in[3];
    const float* Wk   = (const float*)d_in[4];
    const float* bk   = (const float*)d_in[5];
    const float* Wv   = (const float*)d_in[6];
    const float* bv   = (const float*)d_in[7];
    const float* Wpw  = (const float*)d_in[8];
    const float* bpw  = (const float*)d_in[9];
    const float* Wpi  = (const float*)d_in[10];
    const float* bpi  = (const float*)d_in[11];
    const float* Wpo  = (const float*)d_in[12];
    const float* bpo  = (const float*)d_in[13];
    const float* Wg1  = (const float*)d_in[14];
    const float* bg1  = (const float*)d_in[15];
    const float* Wg2  = (const float*)d_in[16];
    const float* bg2  = (const float*)d_in[17];
    float* outp = (float*)d_out;

    const size_t N = (size_t)NB * NCH * PSP;
    const size_t needed = 3 * N * sizeof(short) + 6 * NCH * NCH * sizeof(short)
                        + (3 * 2 * 2560 + 2 * 160 + 6 * 256) * sizeof(float);
    if (ws_size < needed) return;

    short* bufA = (short*)d_ws;          // q_pre, then weight_pre
    short* bufB = bufA + N;              // x, then 'out'
    short* bufC = bufB + N;              // skip_pre
    short* wt16 = bufC + N;              // 6 x 128x128 bf16 weights
    float* kbuf = (float*)(wt16 + 6 * NCH * NCH);
    float* vbuf = kbuf + 2 * 2560;
    float* knb  = vbuf + 2 * 2560;
    float* cbb  = knb + 2 * 2560;
    float* st   = cbb + 2 * 160;
    float* qs   = st;
    float* qs2  = st + 256;
    float* ss   = st + 512;
    float* ss2  = st + 768;
    float* wsu  = st + 1024;
    float* ws2  = st + 1280;

    hipMemsetAsync(st, 0, 6 * 256 * sizeof(float), stream);
    kv_kernel<<<dim3(40), dim3(256), 0, stream>>>(lang, Wk, bk, Wv, bv, kbuf, vbuf);
    wprep_kernel<<<dim3(96), dim3(256), 0, stream>>>(Wq, Wpi, Wpw, Wpo, Wg1, Wg2, wt16);

    const dim3 gg(PSP / (64 * TPB), NB), gb(256);

    g12_kernel<<<gg, gb, 0, stream>>>(img, wt16, bq, bpi, bufA, bufC, qs, qs2, ss, ss2);
    knprep_kernel<<<dim3(NB), dim3(256), 0, stream>>>(qs, qs2, kbuf, knb, cbb);
    attn3_kernel<<<dim3(PSP / 64, NB), gb, 0, stream>>>(bufA, knb, cbb, vbuf, bufB);
    g3_kernel<<<gg, gb, 0, stream>>>(bufB, wt16 + 2 * NCH * NCH, bpw, bufA, wsu, ws2);
    g4_kernel<<<gg, gb, 0, stream>>>(bufC, bufA, ss, ss2, wsu, ws2,
                                     wt16 + 3 * NCH * NCH, bpo, bufB);
    g56_kernel<<<gg, gb, 0, stream>>>(bufB, wt16 + 4 * NCH * NCH, bg1,
                                      wt16 + 5 * NCH * NCH, bg2, outp);
}